// Round 8
// baseline (589.243 us; speedup 1.0000x reference)
//
#include <hip/hip_runtime.h>
#include <hip/hip_bf16.h>

#define BB 4
#define SS 1024
#define HH 1024
#define NHH 16
#define DD 64
#define MAXPOS 1024

typedef __hip_bfloat16 bf16;
typedef unsigned short ushort_t;
typedef __attribute__((ext_vector_type(8))) short short8;
typedef __attribute__((ext_vector_type(4))) float f32x4;
typedef __attribute__((ext_vector_type(4))) unsigned short us4;

#define MFMA_16x16x32(a, b, c) __builtin_amdgcn_mfma_f32_16x16x32_bf16((a), (b), (c), 0, 0, 0)

__device__ __forceinline__ float bu2f(ushort_t u) {
    union { unsigned int i; float f; } c; c.i = ((unsigned int)u) << 16; return c.f;
}
__device__ __forceinline__ ushort_t f2bu(float f) {
    __hip_bfloat16 h = __float2bfloat16(f);
    return *reinterpret_cast<ushort_t*>(&h);
}
// async global->LDS, 16B per lane.  LDS dest must be WAVE-UNIFORM base
// (HW adds lane*16); global src is per-lane.  [m97/m104]
__device__ __forceinline__ void stage16(const ushort_t* g, ushort_t* l) {
    __builtin_amdgcn_global_load_lds(
        (const __attribute__((address_space(1))) void*)g,
        (__attribute__((address_space(3))) void*)l,
        16, 0, 0);
}

// ---------------------------------------------------------------------------
// Kernel 0: all fp32->bf16 conversions in one launch (x, 4 weights, E).
// ---------------------------------------------------------------------------
__global__ void conv_all(const float* __restrict__ x,  const float* __restrict__ Wq,
                         const float* __restrict__ Wk, const float* __restrict__ Wv,
                         const float* __restrict__ Wo, const float* __restrict__ dist,
                         ushort_t* __restrict__ xb,  ushort_t* __restrict__ Wqb,
                         ushort_t* __restrict__ Wkb, ushort_t* __restrict__ Wvb,
                         ushort_t* __restrict__ Wob, ushort_t* __restrict__ Eb)
{
    const int i = blockIdx.x * 256 + threadIdx.x;
    const float* src; ushort_t* dst; int off;
    if (i < 1048576)      { src = x;  dst = xb;  off = i; }
    else if (i < 1310720) { src = Wq; dst = Wqb; off = i - 1048576; }
    else if (i < 1572864) { src = Wk; dst = Wkb; off = i - 1310720; }
    else if (i < 1835008) { src = Wv; dst = Wvb; off = i - 1572864; }
    else if (i < 2097152) { src = Wo; dst = Wob; off = i - 1835008; }
    else if (i < 2129920) {
        const int j = i - 2097152;
        float4 f = (j < 32752) ? ((const float4*)dist)[j] : make_float4(0.f, 0.f, 0.f, 0.f);
        us4 u;
        u[0] = f2bu(f.x); u[1] = f2bu(f.y); u[2] = f2bu(f.z); u[3] = f2bu(f.w);
        ((us4*)Eb)[j] = u;
        return;
    } else return;
    float4 f = ((const float4*)src)[off];
    us4 u;
    u[0] = f2bu(f.x); u[1] = f2bu(f.y); u[2] = f2bu(f.z); u[3] = f2bu(f.w);
    ((us4*)dst)[off] = u;
}

// ---------------------------------------------------------------------------
// Kernel 1a: Q/K projection, MFMA, m97 staging, SWAPPED operands so the
//   C-layout puts per-lane g along the d (output-contiguous) dim:
//   acc[i][j] = MFMA(bf[j], af[i], .) -> C[n = n0+j*16+quad*4+g][m = m0+i*16+lq]
//   epilogue: us4 stores over g (16 vec-stores vs 64 scalar), float4 bias.
//   Q PRE-SCALED by 0.125.  grid (8, 32, 2), block 256.  LDS 16 KB.
// ---------------------------------------------------------------------------
__global__ __launch_bounds__(256)
void qk_mfma(const ushort_t* __restrict__ xb,
             const ushort_t* __restrict__ Wqb, const float* __restrict__ bq,
             const ushort_t* __restrict__ Wkb, const float* __restrict__ bk,
             ushort_t* __restrict__ q, ushort_t* __restrict__ k)
{
    const int which = blockIdx.z;
    const ushort_t* __restrict__ W    = which ? Wkb : Wqb;
    const float*    __restrict__ bias = which ? bk  : bq;
    ushort_t*       __restrict__ out  = which ? k   : q;
    const float sc = which ? 1.0f : 0.125f;

    const int tid = threadIdx.x, w = tid >> 6, lane = tid & 63;
    const int quad = lane >> 4, lq = lane & 15;
    const int wm = w >> 1, wn = w & 1;
    const int bm = blockIdx.y * 128;
    const int bn = blockIdx.x * 128;
    const int m0 = bm + wm * 64;
    const int n0 = bn + wn * 64;

    __shared__ __align__(16) ushort_t As[128 * 32];
    __shared__ __align__(16) ushort_t Bs[128 * 32];

    f32x4 acc[4][4];
#pragma unroll
    for (int i = 0; i < 4; i++)
#pragma unroll
        for (int j = 0; j < 4; j++) acc[i][j] = (f32x4){0.f, 0.f, 0.f, 0.f};

    const int lrow = lane >> 2;
    const int lcol = (lane & 3) * 8;
    const ushort_t* aS0 = xb + (size_t)(bm + w * 16 + lrow) * 1024 + lcol;
    const ushort_t* aS1 = aS0 + 64 * 1024;
    const ushort_t* bS0 = W  + (size_t)(bn + w * 16 + lrow) * 1024 + lcol;
    const ushort_t* bS1 = bS0 + 64 * 1024;
    ushort_t* const aD0 = As + w * 512;
    ushort_t* const aD1 = As + (w + 4) * 512;
    ushort_t* const bD0 = Bs + w * 512;
    ushort_t* const bD1 = Bs + (w + 4) * 512;

    for (int k0 = 0; k0 < 1024; k0 += 32) {
        __syncthreads();
        stage16(aS0 + k0, aD0);
        stage16(aS1 + k0, aD1);
        stage16(bS0 + k0, bD0);
        stage16(bS1 + k0, bD1);
        __syncthreads();

        short8 af[4], bf[4];
#pragma unroll
        for (int i = 0; i < 4; i++)
            af[i] = *(const short8*)&As[(wm * 64 + i * 16 + lq) * 32 + quad * 8];
#pragma unroll
        for (int j = 0; j < 4; j++)
            bf[j] = *(const short8*)&Bs[(wn * 64 + j * 16 + lq) * 32 + quad * 8];
#pragma unroll
        for (int i = 0; i < 4; i++)
#pragma unroll
            for (int j = 0; j < 4; j++)
                acc[i][j] = MFMA_16x16x32(bf[j], af[i], acc[i][j]);   // swapped
    }

    // epilogue: out[((b*NH+h)*S + l)*D + d], us4 over g (d-contiguous)
#pragma unroll
    for (int j = 0; j < 4; j++) {
        const int nb = n0 + j * 16 + quad * 4;     // 4-aligned d-base
        const int h_ = nb >> 6, db = nb & 63;
        const float4 b4 = *(const float4*)&bias[nb];
#pragma unroll
        for (int i = 0; i < 4; i++) {
            const int m  = m0 + i * 16 + lq;
            const int b_ = m >> 10, l = m & 1023;
            us4 pv;
            pv[0] = f2bu((acc[i][j][0] + b4.x) * sc);
            pv[1] = f2bu((acc[i][j][1] + b4.y) * sc);
            pv[2] = f2bu((acc[i][j][2] + b4.z) * sc);
            pv[3] = f2bu((acc[i][j][3] + b4.w) * sc);
            *(us4*)(out + (((size_t)(b_ * NHH) + h_) * SS + l) * DD + db) = pv;
        }
    }
}

// ---------------------------------------------------------------------------
// Kernel 1b: V projection -> V^T [B,NH,D,S], m97 staging, ORIGINAL operand
//   order (V^T epilogue vectorizes over l via g already).  grid (8,32).
// ---------------------------------------------------------------------------
__global__ __launch_bounds__(256)
void v_mfma(const ushort_t* __restrict__ xb,
            const ushort_t* __restrict__ Wvb, const float* __restrict__ bv,
            ushort_t* __restrict__ vt)
{
    const int tid = threadIdx.x, w = tid >> 6, lane = tid & 63;
    const int quad = lane >> 4, lq = lane & 15;
    const int wm = w >> 1, wn = w & 1;
    const int bm = blockIdx.y * 128;
    const int bn = blockIdx.x * 128;
    const int m0 = bm + wm * 64;
    const int n0 = bn + wn * 64;

    __shared__ __align__(16) ushort_t As[128 * 32];
    __shared__ __align__(16) ushort_t Bs[128 * 32];

    f32x4 acc[4][4];
#pragma unroll
    for (int i = 0; i < 4; i++)
#pragma unroll
        for (int j = 0; j < 4; j++) acc[i][j] = (f32x4){0.f, 0.f, 0.f, 0.f};

    const int lrow = lane >> 2;
    const int lcol = (lane & 3) * 8;
    const ushort_t* aS0 = xb  + (size_t)(bm + w * 16 + lrow) * 1024 + lcol;
    const ushort_t* aS1 = aS0 + 64 * 1024;
    const ushort_t* bS0 = Wvb + (size_t)(bn + w * 16 + lrow) * 1024 + lcol;
    const ushort_t* bS1 = bS0 + 64 * 1024;
    ushort_t* const aD0 = As + w * 512;
    ushort_t* const aD1 = As + (w + 4) * 512;
    ushort_t* const bD0 = Bs + w * 512;
    ushort_t* const bD1 = Bs + (w + 4) * 512;

    for (int k0 = 0; k0 < 1024; k0 += 32) {
        __syncthreads();
        stage16(aS0 + k0, aD0);
        stage16(aS1 + k0, aD1);
        stage16(bS0 + k0, bD0);
        stage16(bS1 + k0, bD1);
        __syncthreads();

        short8 af[4], bf[4];
#pragma unroll
        for (int i = 0; i < 4; i++)
            af[i] = *(const short8*)&As[(wm * 64 + i * 16 + lq) * 32 + quad * 8];
#pragma unroll
        for (int j = 0; j < 4; j++)
            bf[j] = *(const short8*)&Bs[(wn * 64 + j * 16 + lq) * 32 + quad * 8];
#pragma unroll
        for (int i = 0; i < 4; i++)
#pragma unroll
            for (int j = 0; j < 4; j++)
                acc[i][j] = MFMA_16x16x32(af[i], bf[j], acc[i][j]);
    }

    // V^T: out[((b*NH+h)*D + d)*S + l], l = m-index (contiguous in g)
#pragma unroll
    for (int j = 0; j < 4; j++) {
        const int n  = n0 + j * 16 + lq;
        const int h_ = n >> 6, d_ = n & 63;
        const float bb = bv[n];
#pragma unroll
        for (int i = 0; i < 4; i++) {
            const int m  = m0 + i * 16 + quad * 4;   // g=0 row
            const int b_ = m >> 10, l = m & 1023;
            us4 pv;
#pragma unroll
            for (int g = 0; g < 4; g++) pv[g] = f2bu(acc[i][j][g] + bb);
            *(us4*)(vt + (((size_t)(b_ * NHH) + h_) * DD + d_) * SS + l) = pv;
        }
    }
}

// ---------------------------------------------------------------------------
// Kernel 2: MFMA flash attention, S^T formulation.  R0 body VERBATIM inside
//   a 2-job outer loop (R8): grid 512, jobs (2s, 2s+1) share (b,h) so job 2
//   re-reads L2-warm K/V/E; all 512 blocks co-resident at exactly 2/CU
//   (no dispatch tail — R0's 1024 = 3-resident phase + 1/CU tail phase).
//   Body ledger (R2-R6): arithmetic/barrier/pin/LDS/swizzle edits ALL
//   regressed; FETCH 71->13.5 MB changed nothing -> not memory-bound.
// grid 512 (1-D), block 256.  LDS 44,032 B.
// ---------------------------------------------------------------------------
__global__ __launch_bounds__(256)
void attn_mfma(const ushort_t* __restrict__ qb, const ushort_t* __restrict__ kb,
               const ushort_t* __restrict__ vt, const ushort_t* __restrict__ Eb,
               const float* __restrict__ mask, ushort_t* __restrict__ ctx)
{
    const int tid  = threadIdx.x;
    const int w    = tid >> 6;
    const int lane = tid & 63;
    const int quad = lane >> 4, lq = lane & 15;

    // LDS: 2*128*68*2 + 64*72*2 = 44,032 B
    __shared__ __align__(16) ushort_t QEsT[128 * 68];   // [t][l]
    __shared__ __align__(16) ushort_t KEsT[128 * 68];   // [t][r]
    __shared__ __align__(16) ushort_t PsT [64 * 72];    // [l][r]

    for (int jj = 0; jj < 2; jj++) {
        const int job = blockIdx.x * 2 + jj;       // (2s,2s+1): same (b,h)
        const int l0  = (job & 15) * 64;
        const int h   = (job >> 4) & 15;
        const int b   = job >> 8;

        const ushort_t* qbh = qb + (size_t)(b * NHH + h) * SS * DD;
        const ushort_t* kbh = kb + (size_t)(b * NHH + h) * SS * DD;
        const ushort_t* vth = vt + (size_t)(b * NHH + h) * DD * SS;   // [d][s]

        // Q B-frag (pre-scaled): rows l = l0 + w*16 + lq
        short8 qa0, qa1;
        {
            const ushort_t* p = qbh + (l0 + w * 16 + lq) * DD + quad * 8;
            qa0 = *(const short8*)p;
            qa1 = *(const short8*)(p + 32);
        }
        const int l_loc = w * 16 + lq;

        f32x4 Oacc[4];
#pragma unroll
        for (int dt = 0; dt < 4; dt++) Oacc[dt] = (f32x4){0.f, 0.f, 0.f, 0.f};
        float mrow = -3e38f, lrow = 0.f;

        for (int rt = 0; rt < 16; rt++) {
            const int r0   = rt * 64;
            const int dmin = l0 - r0 + 960;

            // K fragments (rows r0 + ct*16 + lq)
            short8 kf0[4], kf1[4];
#pragma unroll
            for (int ct = 0; ct < 4; ct++) {
                const ushort_t* p = kbh + (r0 + ct * 16 + lq) * DD + quad * 8;
                kf0[ct] = *(const short8*)p;
                kf1[ct] = *(const short8*)(p + 32);
            }
            // mask values for KE fold (rows r = r0 + w*16 + quad*4 + g)
            float mk[4];
#pragma unroll
            for (int g = 0; g < 4; g++) mk[g] = mask[b * SS + r0 + w * 16 + quad * 4 + g];

            __syncthreads();   // prior tile's QEsT/KEsT reads done

            // --- QE / KE' via MFMA, transposed packed stores ---
#pragma unroll
            for (int tt = 0; tt < 8; tt++) {
                const ushort_t* ep = Eb + (size_t)(dmin + tt * 16 + lq) * DD + quad * 8;
                short8 e0 = *(const short8*)ep;
                short8 e1 = *(const short8*)(ep + 32);
                f32x4 qe = (f32x4){0.f, 0.f, 0.f, 0.f};
                f32x4 ke = (f32x4){0.f, 0.f, 0.f, 0.f};
                qe = MFMA_16x16x32(qa0, e0, qe);
                qe = MFMA_16x16x32(qa1, e1, qe);
                ke = MFMA_16x16x32(kf0[w], e0, ke);
                ke = MFMA_16x16x32(kf1[w], e1, ke);
                us4 pq, pk;
#pragma unroll
                for (int g = 0; g < 4; g++) {
                    pq[g] = f2bu(qe[g]);                       // already /8 via Q
                    pk[g] = f2bu(ke[g] * 0.125f + mk[g]);      // mask folded in
                }
                const int trow = tt * 16 + lq;
                *(us4*)&QEsT[trow * 68 + w * 16 + quad * 4] = pq;
                *(us4*)&KEsT[trow * 68 + w * 16 + quad * 4] = pk;
            }

            // --- S^T = K Q^T for this wave's l-block ---
            f32x4 st[4];
#pragma unroll
            for (int ct = 0; ct < 4; ct++) {
                f32x4 a = (f32x4){0.f, 0.f, 0.f, 0.f};
                a = MFMA_16x16x32(kf0[ct], qa0, a);
                a = MFMA_16x16x32(kf1[ct], qa1, a);
                st[ct] = a;
            }

            __syncthreads();   // QEsT/KEsT visible (KEsT is cross-wave)

            // --- scores + online softmax (per-lane l fixed) ---
            float p[4][4];
            float tmax = -3e38f;
#pragma unroll
            for (int ct = 0; ct < 4; ct++) {
#pragma unroll
                for (int g = 0; g < 4; g++) {
                    const int r_loc = ct * 16 + quad * 4 + g;
                    const int t = l_loc - r_loc + 63;      // [0,126]
                    float s = st[ct][g] + bu2f(QEsT[t * 68 + l_loc])
                                        + bu2f(KEsT[t * 68 + r_loc]);
                    p[ct][g] = s;
                    tmax = fmaxf(tmax, s);
                }
            }
            tmax = fmaxf(tmax, __shfl_xor(tmax, 16));
            tmax = fmaxf(tmax, __shfl_xor(tmax, 32));
            const float mnew  = fmaxf(mrow, tmax);
            const float alpha = __expf(mrow - mnew);
            mrow = mnew;
            float psum = 0.f;
#pragma unroll
            for (int ct = 0; ct < 4; ct++)
#pragma unroll
                for (int g = 0; g < 4; g++) {
                    const float e = __expf(p[ct][g] - mrow);
                    p[ct][g] = e;
                    psum += e;
                }
            psum += __shfl_xor(psum, 16);
            psum += __shfl_xor(psum, 32);
            lrow = lrow * alpha + psum;
#pragma unroll
            for (int dt = 0; dt < 4; dt++)
#pragma unroll
                for (int g = 0; g < 4; g++) Oacc[dt][g] *= alpha;

            // --- P^T -> LDS (wave-local rows, packed) ---
#pragma unroll
            for (int ct = 0; ct < 4; ct++) {
                us4 pp;
#pragma unroll
                for (int g = 0; g < 4; g++) pp[g] = f2bu(p[ct][g]);
                *(us4*)&PsT[l_loc * 72 + ct * 16 + quad * 4] = pp;
            }

            // --- O^T += V^T P^T (no barrier: PsT rows are wave-local) ---
#pragma unroll
            for (int c = 0; c < 2; c++) {
                short8 pb = *(const short8*)&PsT[l_loc * 72 + c * 32 + quad * 8];
#pragma unroll
                for (int dt = 0; dt < 4; dt++) {
                    const ushort_t* vp = vth + (size_t)(dt * 16 + lq) * SS
                                             + r0 + c * 32 + quad * 8;
                    short8 va = *(const short8*)vp;
                    Oacc[dt] = MFMA_16x16x32(va, pb, Oacc[dt]);
                }
            }
        }

        // --- epilogue: ctx[b, l, h*64 + d] bf16, packed us4 over d ---
        const float invl = 1.0f / lrow;
        ushort_t* cbase = ctx + (size_t)(b * SS + l0 + w * 16 + lq) * HH + h * DD;
#pragma unroll
        for (int dt = 0; dt < 4; dt++) {
            us4 po;
#pragma unroll
            for (int g = 0; g < 4; g++) po[g] = f2bu(Oacc[dt][g] * invl);
            *(us4*)(cbase + dt * 16 + quad * 4) = po;
        }
    }
}

// ---------------------------------------------------------------------------
// Kernel 3: output projection, MFMA, m97 staging, SWAPPED operands ->
//   float4 stores/loads over n (g along n).  y = ctx @ Wo^T + bo + x.
// grid (8, 32), block 256.  LDS 16 KB.
// ---------------------------------------------------------------------------
__global__ __launch_bounds__(256)
void out_proj(const ushort_t* __restrict__ ctx, const ushort_t* __restrict__ Wob,
              const float* __restrict__ bo, const float* __restrict__ x,
              float* __restrict__ y)
{
    const int tid = threadIdx.x, w = tid >> 6, lane = tid & 63;
    const int quad = lane >> 4, lq = lane & 15;
    const int wm = w >> 1, wn = w & 1;
    const int bm = blockIdx.y * 128;
    const int bn = blockIdx.x * 128;
    const int m0 = bm + wm * 64;
    const int n0 = bn + wn * 64;

    __shared__ __align__(16) ushort_t As[128 * 32];
    __shared__ __align__(16) ushort_t Bs[128 * 32];

    f32x4 acc[4][4];
#pragma unroll
    for (int i = 0; i < 4; i++)
#pragma unroll
        for (int j = 0; j < 4; j++) acc[i][j] = (f32x4){0.f, 0.f, 0.f, 0.f};

    const int lrow = lane >> 2;
    const int lcol = (lane & 3) * 8;
    const ushort_t* aS0 = ctx + (size_t)(bm + w * 16 + lrow) * 1024 + lcol;
    const ushort_t* aS1 = aS0 + 64 * 1024;
    const ushort_t* bS0 = Wob + (size_t)(bn + w * 16 + lrow) * 1024 + lcol;
    const ushort_t* bS1 = bS0 + 64 * 1024;
    ushort_t* const aD0 = As + w * 512;
    ushort_t* const aD1 = As + (w + 4) * 512;
    ushort_t* const bD0 = Bs + w * 512;
    ushort_t* const bD1 = Bs + (w + 4) * 512;

    for (int k0 = 0; k0 < 1024; k0 += 32) {
        __syncthreads();
        stage16(aS0 + k0, aD0);
        stage16(aS1 + k0, aD1);
        stage16(bS0 + k0, bD0);
        stage16(bS1 + k0, bD1);
        __syncthreads();

        short8 af[4], bf[4];
#pragma unroll
        for (int i = 0; i < 4; i++)
            af[i] = *(const short8*)&As[(wm * 64 + i * 16 + lq) * 32 + quad * 8];
#pragma unroll
        for (int j = 0; j < 4; j++)
            bf[j] = *(const short8*)&Bs[(wn * 64 + j * 16 + lq) * 32 + quad * 8];
#pragma unroll
        for (int i = 0; i < 4; i++)
#pragma unroll
            for (int j = 0; j < 4; j++)
                acc[i][j] = MFMA_16x16x32(bf[j], af[i], acc[i][j]);   // swapped
    }

    // epilogue: float4 over n (16B-aligned), float4 residual + bias loads
#pragma unroll
    for (int j = 0; j < 4; j++) {
        const int nb = n0 + j * 16 + quad * 4;
        const float4 b4 = *(const float4*)&bo[nb];
#pragma unroll
        for (int i = 0; i < 4; i++) {
            const int m = m0 + i * 16 + lq;
            const float4 xr = *(const float4*)&x[(size_t)m * 1024 + nb];
            float4 o;
            o.x = acc[i][j][0] + b4.x + xr.x;
            o.y = acc[i][j][1] + b4.y + xr.y;
            o.z = acc[i][j][2] + b4.z + xr.z;
            o.w = acc[i][j][3] + b4.w + xr.w;
            *(float4*)&y[(size_t)m * 1024 + nb] = o;
        }
    }
}

// ---------------------------------------------------------------------------
// Kernel 4: LayerNorm per row (float4), fp32 out.  grid 4096, block 256.
// ---------------------------------------------------------------------------
__global__ void layernorm(const float* __restrict__ y, const float* __restrict__ g,
                          const float* __restrict__ beta, float* __restrict__ out)
{
    const int row = blockIdx.x;
    const int tid = threadIdx.x;

    __shared__ float red[256];
    __shared__ float red2[256];

    const float4 t4 = *(const float4*)(y + (size_t)row * 1024 + tid * 4);
    float s  = t4.x + t4.y + t4.z + t4.w;
    float s2 = t4.x * t4.x + t4.y * t4.y + t4.z * t4.z + t4.w * t4.w;
    red[tid] = s;
    red2[tid] = s2;
    __syncthreads();
    for (int st = 128; st > 0; st >>= 1) {
        if (tid < st) { red[tid] += red[tid + st]; red2[tid] += red2[tid + st]; }
        __syncthreads();
    }
    const float mu  = red[0] * (1.0f / 1024.0f);
    const float var = red2[0] * (1.0f / 1024.0f) - mu * mu;
    const float rs  = rsqrtf(var + 1e-12f);

    const float4 g4 = *(const float4*)(g + tid * 4);
    const float4 b4 = *(const float4*)(beta + tid * 4);
    float4 o;
    o.x = (t4.x - mu) * rs * g4.x + b4.x;
    o.y = (t4.y - mu) * rs * g4.y + b4.y;
    o.z = (t4.z - mu) * rs * g4.z + b4.z;
    o.w = (t4.w - mu) * rs * g4.w + b4.w;
    *(float4*)(out + (size_t)row * 1024 + tid * 4) = o;
}

// ---------------------------------------------------------------------------
extern "C" void kernel_launch(void* const* d_in, const int* in_sizes, int n_in,
                              void* d_out, int out_size, void* d_ws, size_t ws_size,
                              hipStream_t stream)
{
    const float* x    = (const float*)d_in[0];
    const float* mask = (const float*)d_in[1];
    const float* Wq   = (const float*)d_in[2];
    const float* bq   = (const float*)d_in[3];
    const float* Wk   = (const float*)d_in[4];
    const float* bk   = (const float*)d_in[5];
    const float* Wv   = (const float*)d_in[6];
    const float* bv   = (const float*)d_in[7];
    const float* dist = (const float*)d_in[8];
    const float* Wo   = (const float*)d_in[9];
    const float* bo   = (const float*)d_in[10];
    const float* g    = (const float*)d_in[11];
    const float* be   = (const float*)d_in[12];

    // ws bytes (40.25 MB, <= 44 MB proven-safe):
    //  xb [0,8M) | Wqb [8,10M) Wkb [10,12M) Wvb [12,14M) Wob [14,16M)
    //  qb [16,24M) kb [24,32M) vt [32,40M) (V^T [B,NH,D,S]) | Eb [40,40.25M)
    //  y fp32 overlays [16,32M) (qb/kb dead after attn)
    // d_out scratch: ctx bf16 until layernorm overwrites fp32.
    char* wsb = (char*)d_ws;
    ushort_t* xb  = (ushort_t*)(wsb);
    ushort_t* Wqb = (ushort_t*)(wsb + ( 8u << 20));
    ushort_t* Wkb = (ushort_t*)(wsb + (10u << 20));
    ushort_t* Wvb = (ushort_t*)(wsb + (12u << 20));
    ushort_t* Wob = (ushort_t*)(wsb + (14u << 20));
    ushort_t* qbu = (ushort_t*)(wsb + (16u << 20));
    ushort_t* kbu = (ushort_t*)(wsb + (24u << 20));
    ushort_t* vtb = (ushort_t*)(wsb + (32u << 20));
    ushort_t* Eb  = (ushort_t*)(wsb + (40u << 20));
    float*    y   = (float*)(wsb + (16u << 20));
    ushort_t* ctxb = (ushort_t*)d_out;

    conv_all<<<8320, 256, 0, stream>>>(x, Wq, Wk, Wv, Wo, dist,
                                       xb, Wqb, Wkb, Wvb, Wob, Eb);
    qk_mfma<<<dim3(8, 32, 2), 256, 0, stream>>>(xb, Wqb, bq, Wkb, bk, qbu, kbu);
    v_mfma<<<dim3(8, 32), 256, 0, stream>>>(xb, Wvb, bv, vtb);
    attn_mfma<<<512, 256, 0, stream>>>(qbu, kbu, vtb, Eb, mask, ctxb);
    out_proj<<<dim3(8, 32), 256, 0, stream>>>(ctxb, Wob, bo, x, y);
    layernorm<<<4096, 256, 0, stream>>>(y, g, be, (float*)d_out);
}

// Round 9
// 413.795 us; speedup vs baseline: 1.4240x; 1.4240x over previous
//
#include <hip/hip_runtime.h>
#include <hip/hip_bf16.h>

#define BB 4
#define SS 1024
#define HH 1024
#define NHH 16
#define DD 64
#define MAXPOS 1024

typedef __hip_bfloat16 bf16;
typedef unsigned short ushort_t;
typedef __attribute__((ext_vector_type(8))) short short8;
typedef __attribute__((ext_vector_type(4))) float f32x4;
typedef __attribute__((ext_vector_type(4))) unsigned short us4;

#define MFMA_16x16x32(a, b, c) __builtin_amdgcn_mfma_f32_16x16x32_bf16((a), (b), (c), 0, 0, 0)

__device__ __forceinline__ float bu2f(ushort_t u) {
    union { unsigned int i; float f; } c; c.i = ((unsigned int)u) << 16; return c.f;
}
__device__ __forceinline__ ushort_t f2bu(float f) {
    __hip_bfloat16 h = __float2bfloat16(f);
    return *reinterpret_cast<ushort_t*>(&h);
}
// async global->LDS, 16B per lane.  LDS dest must be WAVE-UNIFORM base
// (HW adds lane*16); global src is per-lane.  [m97/m104]
__device__ __forceinline__ void stage16(const ushort_t* g, ushort_t* l) {
    __builtin_amdgcn_global_load_lds(
        (const __attribute__((address_space(1))) void*)g,
        (__attribute__((address_space(3))) void*)l,
        16, 0, 0);
}

// ---------------------------------------------------------------------------
// Kernel 0: all fp32->bf16 conversions in one launch (x, 4 weights, E).
// Segments in units of float4/us4 groups:
//   x [0, 1048576) | Wq +262144 | Wk | Wv | Wo -> 2097152 | E [.., 2129920)
// E: 2047*64 = 131008 valid floats = 32752 groups; rest zero (row 2047).
// ---------------------------------------------------------------------------
__global__ void conv_all(const float* __restrict__ x,  const float* __restrict__ Wq,
                         const float* __restrict__ Wk, const float* __restrict__ Wv,
                         const float* __restrict__ Wo, const float* __restrict__ dist,
                         ushort_t* __restrict__ xb,  ushort_t* __restrict__ Wqb,
                         ushort_t* __restrict__ Wkb, ushort_t* __restrict__ Wvb,
                         ushort_t* __restrict__ Wob, ushort_t* __restrict__ Eb)
{
    const int i = blockIdx.x * 256 + threadIdx.x;
    const float* src; ushort_t* dst; int off;
    if (i < 1048576)      { src = x;  dst = xb;  off = i; }
    else if (i < 1310720) { src = Wq; dst = Wqb; off = i - 1048576; }
    else if (i < 1572864) { src = Wk; dst = Wkb; off = i - 1310720; }
    else if (i < 1835008) { src = Wv; dst = Wvb; off = i - 1572864; }
    else if (i < 2097152) { src = Wo; dst = Wob; off = i - 1835008; }
    else if (i < 2129920) {
        const int j = i - 2097152;
        float4 f = (j < 32752) ? ((const float4*)dist)[j] : make_float4(0.f, 0.f, 0.f, 0.f);
        us4 u;
        u[0] = f2bu(f.x); u[1] = f2bu(f.y); u[2] = f2bu(f.z); u[3] = f2bu(f.w);
        ((us4*)Eb)[j] = u;
        return;
    } else return;
    float4 f = ((const float4*)src)[off];
    us4 u;
    u[0] = f2bu(f.x); u[1] = f2bu(f.y); u[2] = f2bu(f.z); u[3] = f2bu(f.w);
    ((us4*)dst)[off] = u;
}

// ---------------------------------------------------------------------------
// Kernel 1: QKV projection, MFMA.  C = xb @ W^T (+bias).
//   m97-structure staging — A/B tiles [128][32] in LDS via
//   global_load_lds width 16, 2 barriers/K-step.
//   Q -> [B,NH,S,D], PRE-SCALED by 0.125 (exact in bf16)
//   K -> [B,NH,S,D]
//   V -> [B,NH,D,S]  (transposed: PV A-operand reads rows of V^T directly)
// grid (8, 32, 3), block 256 (4 waves, 2x2 of 64x64).  LDS 16 KB.
// ---------------------------------------------------------------------------
__global__ __launch_bounds__(256)
void qkv_mfma(const ushort_t* __restrict__ xb,
              const ushort_t* __restrict__ Wqb, const float* __restrict__ bq,
              const ushort_t* __restrict__ Wkb, const float* __restrict__ bk,
              const ushort_t* __restrict__ Wvb, const float* __restrict__ bv,
              ushort_t* __restrict__ q, ushort_t* __restrict__ k,
              ushort_t* __restrict__ vt)
{
    const int which = blockIdx.z;
    const ushort_t* __restrict__ W    = (which == 0) ? Wqb : (which == 1) ? Wkb : Wvb;
    const float*    __restrict__ bias = (which == 0) ? bq  : (which == 1) ? bk  : bv;

    const int tid = threadIdx.x, w = tid >> 6, lane = tid & 63;
    const int quad = lane >> 4, lq = lane & 15;
    const int wm = w >> 1, wn = w & 1;
    const int bm = blockIdx.y * 128;          // block row base
    const int bn = blockIdx.x * 128;          // block col base
    const int m0 = bm + wm * 64;
    const int n0 = bn + wn * 64;

    __shared__ __align__(16) ushort_t As[128 * 32];   // rows bm..bm+127, cols k0..k0+31
    __shared__ __align__(16) ushort_t Bs[128 * 32];   // rows bn..bn+127

    f32x4 acc[4][4];
#pragma unroll
    for (int i = 0; i < 4; i++)
#pragma unroll
        for (int j = 0; j < 4; j++) acc[i][j] = (f32x4){0.f, 0.f, 0.f, 0.f};

    // Staging map: chunk c (1024 B = 16 rows) at LDS byte c*1024 + lane*16.
    // lane L -> row c*16 + L/4, col (L&3)*8 (bf16).  Wave w covers c=w, w+4.
    const int lrow = lane >> 2;
    const int lcol = (lane & 3) * 8;
    const ushort_t* aS0 = xb + (size_t)(bm + w * 16 + lrow) * 1024 + lcol;
    const ushort_t* aS1 = aS0 + 64 * 1024;     // chunk w+4 = +64 rows
    const ushort_t* bS0 = W  + (size_t)(bn + w * 16 + lrow) * 1024 + lcol;
    const ushort_t* bS1 = bS0 + 64 * 1024;
    ushort_t* const aD0 = As + w * 512;        // wave-uniform LDS bases
    ushort_t* const aD1 = As + (w + 4) * 512;
    ushort_t* const bD0 = Bs + w * 512;
    ushort_t* const bD1 = Bs + (w + 4) * 512;

    for (int k0 = 0; k0 < 1024; k0 += 32) {
        __syncthreads();                       // prior iter's ds_reads done
        stage16(aS0 + k0, aD0);
        stage16(aS1 + k0, aD1);
        stage16(bS0 + k0, bD0);
        stage16(bS1 + k0, bD1);
        __syncthreads();                       // vmcnt(0) drained by barrier

        short8 af[4], bf[4];
#pragma unroll
        for (int i = 0; i < 4; i++)
            af[i] = *(const short8*)&As[(wm * 64 + i * 16 + lq) * 32 + quad * 8];
#pragma unroll
        for (int j = 0; j < 4; j++)
            bf[j] = *(const short8*)&Bs[(wn * 64 + j * 16 + lq) * 32 + quad * 8];
#pragma unroll
        for (int i = 0; i < 4; i++)
#pragma unroll
            for (int j = 0; j < 4; j++)
                acc[i][j] = MFMA_16x16x32(af[i], bf[j], acc[i][j]);
    }

    if (which == 2) {
        // V^T: out[((b*NH+h)*D + d)*S + l], l = m-index (contiguous in g)
#pragma unroll
        for (int j = 0; j < 4; j++) {
            const int n  = n0 + j * 16 + lq;
            const int h_ = n >> 6, d_ = n & 63;
            const float bb = bias[n];
#pragma unroll
            for (int i = 0; i < 4; i++) {
                const int m  = m0 + i * 16 + quad * 4;   // g=0 row
                const int b_ = m >> 10, l = m & 1023;
                us4 pv;
#pragma unroll
                for (int g = 0; g < 4; g++) pv[g] = f2bu(acc[i][j][g] + bb);
                *(us4*)(vt + (((size_t)(b_ * NHH) + h_) * DD + d_) * SS + l) = pv;
            }
        }
    } else {
        ushort_t* __restrict__ out = (which == 0) ? q : k;
        const float sc = (which == 0) ? 0.125f : 1.0f;
#pragma unroll
        for (int j = 0; j < 4; j++) {
            const int n  = n0 + j * 16 + lq;
            const int h_ = n >> 6, d_ = n & 63;
            const float bb = bias[n];
#pragma unroll
            for (int i = 0; i < 4; i++) {
#pragma unroll
                for (int g = 0; g < 4; g++) {
                    const int m  = m0 + i * 16 + quad * 4 + g;
                    const int b_ = m >> 10, l = m & 1023;
                    out[(((size_t)(b_ * NHH) + h_) * SS + l) * DD + d_] =
                        f2bu((acc[i][j][g] + bb) * sc);
                }
            }
        }
    }
}

// ---------------------------------------------------------------------------
// Kernel 2: MFMA flash attention, S^T formulation.  R0 VERBATIM (254 us).
//   Ledger (R2-R8): body arithmetic, barrier structure, occupancy pin, LDS
//   footprint, XCD swizzle, and 2-job outer loop ALL regressed.
//   R6: FETCH 71->13.5 MB changed nothing -> not memory-bound.
//   R8: full co-residency (512 blocks = 2/CU exact) left occupancy at 23%
//   -> per-wave latency-bound; 23% is the body's operating point.
//   Do not edit this kernel.
//   S^T = K Q^T  (Q pre-scaled by 1/8)  -> C[r=quad*4+g][l=lq] per 16x16
//   QE = Q E^T, KE' = (K E^T)*0.125 + mask  -> transposed packed LDS stores
//   score = S^T + QE[l][t] + KE'[r][t],  t = l_loc - r_loc + 63
//   softmax over r (per-lane scalar state, cross-quad shuffles)
//   P^T packs straight from C-registers -> wave-local LDS -> B-operand
//   O^T += V^T P^T  (V^T A-frags direct from global)
// grid (16, 16, 4), block 256.  LDS 44,032 B.
// ---------------------------------------------------------------------------
__global__ __launch_bounds__(256)
void attn_mfma(const ushort_t* __restrict__ qb, const ushort_t* __restrict__ kb,
               const ushort_t* __restrict__ vt, const ushort_t* __restrict__ Eb,
               const float* __restrict__ mask, ushort_t* __restrict__ ctx)
{
    const int l0 = blockIdx.x * 64;
    const int h  = blockIdx.y, b = blockIdx.z;
    const int tid  = threadIdx.x;
    const int w    = tid >> 6;
    const int lane = tid & 63;
    const int quad = lane >> 4, lq = lane & 15;

    // LDS: 2*128*68*2 + 64*72*2 = 44,032 B
    __shared__ __align__(16) ushort_t QEsT[128 * 68];   // [t][l]
    __shared__ __align__(16) ushort_t KEsT[128 * 68];   // [t][r]
    __shared__ __align__(16) ushort_t PsT [64 * 72];    // [l][r]

    const ushort_t* qbh = qb + (size_t)(b * NHH + h) * SS * DD;
    const ushort_t* kbh = kb + (size_t)(b * NHH + h) * SS * DD;
    const ushort_t* vth = vt + (size_t)(b * NHH + h) * DD * SS;   // [d][s]

    // Q B-frag (pre-scaled): rows l = l0 + w*16 + lq
    short8 qa0, qa1;
    {
        const ushort_t* p = qbh + (l0 + w * 16 + lq) * DD + quad * 8;
        qa0 = *(const short8*)p;
        qa1 = *(const short8*)(p + 32);
    }
    const int l_loc = w * 16 + lq;

    f32x4 Oacc[4];
#pragma unroll
    for (int dt = 0; dt < 4; dt++) Oacc[dt] = (f32x4){0.f, 0.f, 0.f, 0.f};
    float mrow = -3e38f, lrow = 0.f;

    for (int rt = 0; rt < 16; rt++) {
        const int r0   = rt * 64;
        const int dmin = l0 - r0 + 960;

        // K fragments (rows r0 + ct*16 + lq)
        short8 kf0[4], kf1[4];
#pragma unroll
        for (int ct = 0; ct < 4; ct++) {
            const ushort_t* p = kbh + (r0 + ct * 16 + lq) * DD + quad * 8;
            kf0[ct] = *(const short8*)p;
            kf1[ct] = *(const short8*)(p + 32);
        }
        // mask values for KE fold (rows r = r0 + w*16 + quad*4 + g)
        float mk[4];
#pragma unroll
        for (int g = 0; g < 4; g++) mk[g] = mask[b * SS + r0 + w * 16 + quad * 4 + g];

        __syncthreads();   // prior tile's QEsT/KEsT reads done

        // --- QE / KE' via MFMA, transposed packed stores ---
#pragma unroll
        for (int tt = 0; tt < 8; tt++) {
            const ushort_t* ep = Eb + (size_t)(dmin + tt * 16 + lq) * DD + quad * 8;
            short8 e0 = *(const short8*)ep;
            short8 e1 = *(const short8*)(ep + 32);
            f32x4 qe = (f32x4){0.f, 0.f, 0.f, 0.f};
            f32x4 ke = (f32x4){0.f, 0.f, 0.f, 0.f};
            qe = MFMA_16x16x32(qa0, e0, qe);
            qe = MFMA_16x16x32(qa1, e1, qe);
            ke = MFMA_16x16x32(kf0[w], e0, ke);
            ke = MFMA_16x16x32(kf1[w], e1, ke);
            us4 pq, pk;
#pragma unroll
            for (int g = 0; g < 4; g++) {
                pq[g] = f2bu(qe[g]);                       // already /8 via Q
                pk[g] = f2bu(ke[g] * 0.125f + mk[g]);      // mask folded in
            }
            const int trow = tt * 16 + lq;
            *(us4*)&QEsT[trow * 68 + w * 16 + quad * 4] = pq;
            *(us4*)&KEsT[trow * 68 + w * 16 + quad * 4] = pk;
        }

        // --- S^T = K Q^T for this wave's l-block ---
        f32x4 st[4];
#pragma unroll
        for (int ct = 0; ct < 4; ct++) {
            f32x4 a = (f32x4){0.f, 0.f, 0.f, 0.f};
            a = MFMA_16x16x32(kf0[ct], qa0, a);
            a = MFMA_16x16x32(kf1[ct], qa1, a);
            st[ct] = a;
        }

        __syncthreads();   // QEsT/KEsT visible (KEsT is cross-wave)

        // --- scores + online softmax (per-lane l fixed) ---
        float p[4][4];
        float tmax = -3e38f;
#pragma unroll
        for (int ct = 0; ct < 4; ct++) {
#pragma unroll
            for (int g = 0; g < 4; g++) {
                const int r_loc = ct * 16 + quad * 4 + g;
                const int t = l_loc - r_loc + 63;      // [0,126]
                float s = st[ct][g] + bu2f(QEsT[t * 68 + l_loc])
                                    + bu2f(KEsT[t * 68 + r_loc]);
                p[ct][g] = s;
                tmax = fmaxf(tmax, s);
            }
        }
        tmax = fmaxf(tmax, __shfl_xor(tmax, 16));
        tmax = fmaxf(tmax, __shfl_xor(tmax, 32));
        const float mnew  = fmaxf(mrow, tmax);
        const float alpha = __expf(mrow - mnew);
        mrow = mnew;
        float psum = 0.f;
#pragma unroll
        for (int ct = 0; ct < 4; ct++)
#pragma unroll
            for (int g = 0; g < 4; g++) {
                const float e = __expf(p[ct][g] - mrow);
                p[ct][g] = e;
                psum += e;
            }
        psum += __shfl_xor(psum, 16);
        psum += __shfl_xor(psum, 32);
        lrow = lrow * alpha + psum;
#pragma unroll
        for (int dt = 0; dt < 4; dt++)
#pragma unroll
            for (int g = 0; g < 4; g++) Oacc[dt][g] *= alpha;

        // --- P^T -> LDS (wave-local rows, packed) ---
#pragma unroll
        for (int ct = 0; ct < 4; ct++) {
            us4 pp;
#pragma unroll
            for (int g = 0; g < 4; g++) pp[g] = f2bu(p[ct][g]);
            *(us4*)&PsT[l_loc * 72 + ct * 16 + quad * 4] = pp;
        }

        // --- O^T += V^T P^T (no barrier: PsT rows are wave-local) ---
#pragma unroll
        for (int c = 0; c < 2; c++) {
            short8 pb = *(const short8*)&PsT[l_loc * 72 + c * 32 + quad * 8];
#pragma unroll
            for (int dt = 0; dt < 4; dt++) {
                const ushort_t* vp = vth + (size_t)(dt * 16 + lq) * SS
                                         + r0 + c * 32 + quad * 8;
                short8 va = *(const short8*)vp;
                Oacc[dt] = MFMA_16x16x32(va, pb, Oacc[dt]);
            }
        }
    }

    // --- epilogue: ctx[b, l, h*64 + d] bf16, packed us4 over d ---
    const float invl = 1.0f / lrow;
    ushort_t* cbase = ctx + (size_t)(b * SS + l0 + w * 16 + lq) * HH + h * DD;
#pragma unroll
    for (int dt = 0; dt < 4; dt++) {
        us4 po;
#pragma unroll
        for (int g = 0; g < 4; g++) po[g] = f2bu(Oacc[dt][g] * invl);
        *(us4*)(cbase + dt * 16 + quad * 4) = po;
    }
}

// ---------------------------------------------------------------------------
// Kernel 3: output projection, MFMA.  y = ctx @ Wo^T + bo + x  (fp32 out).
//   m97-structure staging; tile 128x128.
// grid (8, 32), block 256 (4 waves, 2x2 of 64x64).  LDS 16 KB.
// ---------------------------------------------------------------------------
__global__ __launch_bounds__(256)
void out_proj(const ushort_t* __restrict__ ctx, const ushort_t* __restrict__ Wob,
              const float* __restrict__ bo, const float* __restrict__ x,
              float* __restrict__ y)
{
    const int tid = threadIdx.x, w = tid >> 6, lane = tid & 63;
    const int quad = lane >> 4, lq = lane & 15;
    const int wm = w >> 1, wn = w & 1;
    const int bm = blockIdx.y * 128;
    const int bn = blockIdx.x * 128;
    const int m0 = bm + wm * 64;
    const int n0 = bn + wn * 64;

    __shared__ __align__(16) ushort_t As[128 * 32];
    __shared__ __align__(16) ushort_t Bs[128 * 32];

    f32x4 acc[4][4];
#pragma unroll
    for (int i = 0; i < 4; i++)
#pragma unroll
        for (int j = 0; j < 4; j++) acc[i][j] = (f32x4){0.f, 0.f, 0.f, 0.f};

    const int lrow = lane >> 2;
    const int lcol = (lane & 3) * 8;
    const ushort_t* aS0 = ctx + (size_t)(bm + w * 16 + lrow) * 1024 + lcol;
    const ushort_t* aS1 = aS0 + 64 * 1024;
    const ushort_t* bS0 = Wob + (size_t)(bn + w * 16 + lrow) * 1024 + lcol;
    const ushort_t* bS1 = bS0 + 64 * 1024;
    ushort_t* const aD0 = As + w * 512;
    ushort_t* const aD1 = As + (w + 4) * 512;
    ushort_t* const bD0 = Bs + w * 512;
    ushort_t* const bD1 = Bs + (w + 4) * 512;

    for (int k0 = 0; k0 < 1024; k0 += 32) {
        __syncthreads();
        stage16(aS0 + k0, aD0);
        stage16(aS1 + k0, aD1);
        stage16(bS0 + k0, bD0);
        stage16(bS1 + k0, bD1);
        __syncthreads();

        short8 af[4], bf[4];
#pragma unroll
        for (int i = 0; i < 4; i++)
            af[i] = *(const short8*)&As[(wm * 64 + i * 16 + lq) * 32 + quad * 8];
#pragma unroll
        for (int j = 0; j < 4; j++)
            bf[j] = *(const short8*)&Bs[(wn * 64 + j * 16 + lq) * 32 + quad * 8];
#pragma unroll
        for (int i = 0; i < 4; i++)
#pragma unroll
            for (int j = 0; j < 4; j++)
                acc[i][j] = MFMA_16x16x32(af[i], bf[j], acc[i][j]);
    }

#pragma unroll
    for (int j = 0; j < 4; j++) {
        const int n = n0 + j * 16 + lq;
        const float bb = bo[n];
#pragma unroll
        for (int i = 0; i < 4; i++) {
#pragma unroll
            for (int g = 0; g < 4; g++) {
                const int m = m0 + i * 16 + quad * 4 + g;
                y[(size_t)m * 1024 + n] = acc[i][j][g] + bb + x[(size_t)m * 1024 + n];
            }
        }
    }
}

// ---------------------------------------------------------------------------
// Kernel 4: LayerNorm per row (float4), fp32 out.  grid 4096, block 256.
// ---------------------------------------------------------------------------
__global__ void layernorm(const float* __restrict__ y, const float* __restrict__ g,
                          const float* __restrict__ beta, float* __restrict__ out)
{
    const int row = blockIdx.x;
    const int tid = threadIdx.x;

    __shared__ float red[256];
    __shared__ float red2[256];

    const float4 t4 = *(const float4*)(y + (size_t)row * 1024 + tid * 4);
    float s  = t4.x + t4.y + t4.z + t4.w;
    float s2 = t4.x * t4.x + t4.y * t4.y + t4.z * t4.z + t4.w * t4.w;
    red[tid] = s;
    red2[tid] = s2;
    __syncthreads();
    for (int st = 128; st > 0; st >>= 1) {
        if (tid < st) { red[tid] += red[tid + st]; red2[tid] += red2[tid + st]; }
        __syncthreads();
    }
    const float mu  = red[0] * (1.0f / 1024.0f);
    const float var = red2[0] * (1.0f / 1024.0f) - mu * mu;
    const float rs  = rsqrtf(var + 1e-12f);

    const float4 g4 = *(const float4*)(g + tid * 4);
    const float4 b4 = *(const float4*)(beta + tid * 4);
    float4 o;
    o.x = (t4.x - mu) * rs * g4.x + b4.x;
    o.y = (t4.y - mu) * rs * g4.y + b4.y;
    o.z = (t4.z - mu) * rs * g4.z + b4.z;
    o.w = (t4.w - mu) * rs * g4.w + b4.w;
    *(float4*)(out + (size_t)row * 1024 + tid * 4) = o;
}

// ---------------------------------------------------------------------------
extern "C" void kernel_launch(void* const* d_in, const int* in_sizes, int n_in,
                              void* d_out, int out_size, void* d_ws, size_t ws_size,
                              hipStream_t stream)
{
    const float* x    = (const float*)d_in[0];
    const float* mask = (const float*)d_in[1];
    const float* Wq   = (const float*)d_in[2];
    const float* bq   = (const float*)d_in[3];
    const float* Wk   = (const float*)d_in[4];
    const float* bk   = (const float*)d_in[5];
    const float* Wv   = (const float*)d_in[6];
    const float* bv   = (const float*)d_in[7];
    const float* dist = (const float*)d_in[8];
    const float* Wo   = (const float*)d_in[9];
    const float* bo   = (const float*)d_in[10];
    const float* g    = (const float*)d_in[11];
    const float* be   = (const float*)d_in[12];

    // ws bytes (40.25 MB, <= 44 MB proven-safe):
    //  xb [0,8M) | Wqb [8,10M) Wkb [10,12M) Wvb [12,14M) Wob [14,16M)
    //  qb [16,24M) kb [24,32M) vt [32,40M) (V^T [B,NH,D,S]) | Eb [40,40.25M)
    //  y fp32 overlays [16,32M) (qb/kb dead after attn)
    // d_out scratch: ctx bf16 until layernorm overwrites fp32.
    char* wsb = (char*)d_ws;
    ushort_t* xb  = (ushort_t*)(wsb);
    ushort_t* Wqb = (ushort_t*)(wsb + ( 8u << 20));
    ushort_t* Wkb = (ushort_t*)(wsb + (10u << 20));
    ushort_t* Wvb = (ushort_t*)(wsb + (12u << 20));
    ushort_t* Wob = (ushort_t*)(wsb + (14u << 20));
    ushort_t* qbu = (ushort_t*)(wsb + (16u << 20));
    ushort_t* kbu = (ushort_t*)(wsb + (24u << 20));
    ushort_t* vtb = (ushort_t*)(wsb + (32u << 20));
    ushort_t* Eb  = (ushort_t*)(wsb + (40u << 20));
    float*    y   = (float*)(wsb + (16u << 20));
    ushort_t* ctxb = (ushort_t*)d_out;

    conv_all<<<8320, 256, 0, stream>>>(x, Wq, Wk, Wv, Wo, dist,
                                       xb, Wqb, Wkb, Wvb, Wob, Eb);
    qkv_mfma<<<dim3(8, 32, 3), 256, 0, stream>>>(xb, Wqb, bq, Wkb, bk, Wvb, bv,
                                                 qbu, kbu, vtb);
    attn_mfma<<<dim3(16, 16, 4), 256, 0, stream>>>(qbu, kbu, vtb, Eb, mask, ctxb);
    out_proj<<<dim3(8, 32), 256, 0, stream>>>(ctxb, Wob, bo, x, y);
    layernorm<<<4096, 256, 0, stream>>>(y, g, be, (float*)d_out);
}

// Round 10
// 406.510 us; speedup vs baseline: 1.4495x; 1.0179x over previous
//
#include <hip/hip_runtime.h>
#include <hip/hip_bf16.h>

#define BB 4
#define SS 1024
#define HH 1024
#define NHH 16
#define DD 64
#define MAXPOS 1024

typedef __hip_bfloat16 bf16;
typedef unsigned short ushort_t;
typedef __attribute__((ext_vector_type(8))) short short8;
typedef __attribute__((ext_vector_type(4))) float f32x4;
typedef __attribute__((ext_vector_type(4))) unsigned short us4;

#define MFMA_16x16x32(a, b, c) __builtin_amdgcn_mfma_f32_16x16x32_bf16((a), (b), (c), 0, 0, 0)

__device__ __forceinline__ float bu2f(ushort_t u) {
    union { unsigned int i; float f; } c; c.i = ((unsigned int)u) << 16; return c.f;
}
__device__ __forceinline__ ushort_t f2bu(float f) {
    __hip_bfloat16 h = __float2bfloat16(f);
    return *reinterpret_cast<ushort_t*>(&h);
}
// async global->LDS, 16B per lane.  LDS dest must be WAVE-UNIFORM base
// (HW adds lane*16); global src is per-lane.  [m97/m104]
__device__ __forceinline__ void stage16(const ushort_t* g, ushort_t* l) {
    __builtin_amdgcn_global_load_lds(
        (const __attribute__((address_space(1))) void*)g,
        (__attribute__((address_space(3))) void*)l,
        16, 0, 0);
}

// ---------------------------------------------------------------------------
// Kernel 0: all fp32->bf16 conversions in one launch (x, 4 weights, E).
// Segments in units of float4/us4 groups:
//   x [0, 1048576) | Wq +262144 | Wk | Wv | Wo -> 2097152 | E [.., 2129920)
// E: 2047*64 = 131008 valid floats = 32752 groups; rest zero (row 2047).
// ---------------------------------------------------------------------------
__global__ void conv_all(const float* __restrict__ x,  const float* __restrict__ Wq,
                         const float* __restrict__ Wk, const float* __restrict__ Wv,
                         const float* __restrict__ Wo, const float* __restrict__ dist,
                         ushort_t* __restrict__ xb,  ushort_t* __restrict__ Wqb,
                         ushort_t* __restrict__ Wkb, ushort_t* __restrict__ Wvb,
                         ushort_t* __restrict__ Wob, ushort_t* __restrict__ Eb)
{
    const int i = blockIdx.x * 256 + threadIdx.x;
    const float* src; ushort_t* dst; int off;
    if (i < 1048576)      { src = x;  dst = xb;  off = i; }
    else if (i < 1310720) { src = Wq; dst = Wqb; off = i - 1048576; }
    else if (i < 1572864) { src = Wk; dst = Wkb; off = i - 1310720; }
    else if (i < 1835008) { src = Wv; dst = Wvb; off = i - 1572864; }
    else if (i < 2097152) { src = Wo; dst = Wob; off = i - 1835008; }
    else if (i < 2129920) {
        const int j = i - 2097152;
        float4 f = (j < 32752) ? ((const float4*)dist)[j] : make_float4(0.f, 0.f, 0.f, 0.f);
        us4 u;
        u[0] = f2bu(f.x); u[1] = f2bu(f.y); u[2] = f2bu(f.z); u[3] = f2bu(f.w);
        ((us4*)Eb)[j] = u;
        return;
    } else return;
    float4 f = ((const float4*)src)[off];
    us4 u;
    u[0] = f2bu(f.x); u[1] = f2bu(f.y); u[2] = f2bu(f.z); u[3] = f2bu(f.w);
    ((us4*)dst)[off] = u;
}

// ---------------------------------------------------------------------------
// Kernel 1: QKV projection, MFMA.  C = xb @ W^T (+bias).
//   m97-structure staging — A/B tiles [128][32] in LDS via
//   global_load_lds width 16, 2 barriers/K-step.
//   Q -> [B,NH,S,D], PRE-SCALED by 0.125 (exact in bf16)
//   K -> [B,NH,S,D]
//   V -> [B,NH,D,S]  (transposed: PV A-operand reads rows of V^T directly)
// grid (8, 32, 3), block 256 (4 waves, 2x2 of 64x64).  LDS 16 KB.
// ---------------------------------------------------------------------------
__global__ __launch_bounds__(256)
void qkv_mfma(const ushort_t* __restrict__ xb,
              const ushort_t* __restrict__ Wqb, const float* __restrict__ bq,
              const ushort_t* __restrict__ Wkb, const float* __restrict__ bk,
              const ushort_t* __restrict__ Wvb, const float* __restrict__ bv,
              ushort_t* __restrict__ q, ushort_t* __restrict__ k,
              ushort_t* __restrict__ vt)
{
    const int which = blockIdx.z;
    const ushort_t* __restrict__ W    = (which == 0) ? Wqb : (which == 1) ? Wkb : Wvb;
    const float*    __restrict__ bias = (which == 0) ? bq  : (which == 1) ? bk  : bv;

    const int tid = threadIdx.x, w = tid >> 6, lane = tid & 63;
    const int quad = lane >> 4, lq = lane & 15;
    const int wm = w >> 1, wn = w & 1;
    const int bm = blockIdx.y * 128;          // block row base
    const int bn = blockIdx.x * 128;          // block col base
    const int m0 = bm + wm * 64;
    const int n0 = bn + wn * 64;

    __shared__ __align__(16) ushort_t As[128 * 32];   // rows bm..bm+127, cols k0..k0+31
    __shared__ __align__(16) ushort_t Bs[128 * 32];   // rows bn..bn+127

    f32x4 acc[4][4];
#pragma unroll
    for (int i = 0; i < 4; i++)
#pragma unroll
        for (int j = 0; j < 4; j++) acc[i][j] = (f32x4){0.f, 0.f, 0.f, 0.f};

    // Staging map: chunk c (1024 B = 16 rows) at LDS byte c*1024 + lane*16.
    // lane L -> row c*16 + L/4, col (L&3)*8 (bf16).  Wave w covers c=w, w+4.
    const int lrow = lane >> 2;
    const int lcol = (lane & 3) * 8;
    const ushort_t* aS0 = xb + (size_t)(bm + w * 16 + lrow) * 1024 + lcol;
    const ushort_t* aS1 = aS0 + 64 * 1024;     // chunk w+4 = +64 rows
    const ushort_t* bS0 = W  + (size_t)(bn + w * 16 + lrow) * 1024 + lcol;
    const ushort_t* bS1 = bS0 + 64 * 1024;
    ushort_t* const aD0 = As + w * 512;        // wave-uniform LDS bases
    ushort_t* const aD1 = As + (w + 4) * 512;
    ushort_t* const bD0 = Bs + w * 512;
    ushort_t* const bD1 = Bs + (w + 4) * 512;

    for (int k0 = 0; k0 < 1024; k0 += 32) {
        __syncthreads();                       // prior iter's ds_reads done
        stage16(aS0 + k0, aD0);
        stage16(aS1 + k0, aD1);
        stage16(bS0 + k0, bD0);
        stage16(bS1 + k0, bD1);
        __syncthreads();                       // vmcnt(0) drained by barrier

        short8 af[4], bf[4];
#pragma unroll
        for (int i = 0; i < 4; i++)
            af[i] = *(const short8*)&As[(wm * 64 + i * 16 + lq) * 32 + quad * 8];
#pragma unroll
        for (int j = 0; j < 4; j++)
            bf[j] = *(const short8*)&Bs[(wn * 64 + j * 16 + lq) * 32 + quad * 8];
#pragma unroll
        for (int i = 0; i < 4; i++)
#pragma unroll
            for (int j = 0; j < 4; j++)
                acc[i][j] = MFMA_16x16x32(af[i], bf[j], acc[i][j]);
    }

    if (which == 2) {
        // V^T: out[((b*NH+h)*D + d)*S + l], l = m-index (contiguous in g)
#pragma unroll
        for (int j = 0; j < 4; j++) {
            const int n  = n0 + j * 16 + lq;
            const int h_ = n >> 6, d_ = n & 63;
            const float bb = bias[n];
#pragma unroll
            for (int i = 0; i < 4; i++) {
                const int m  = m0 + i * 16 + quad * 4;   // g=0 row
                const int b_ = m >> 10, l = m & 1023;
                us4 pv;
#pragma unroll
                for (int g = 0; g < 4; g++) pv[g] = f2bu(acc[i][j][g] + bb);
                *(us4*)(vt + (((size_t)(b_ * NHH) + h_) * DD + d_) * SS + l) = pv;
            }
        }
    } else {
        ushort_t* __restrict__ out = (which == 0) ? q : k;
        const float sc = (which == 0) ? 0.125f : 1.0f;
#pragma unroll
        for (int j = 0; j < 4; j++) {
            const int n  = n0 + j * 16 + lq;
            const int h_ = n >> 6, d_ = n & 63;
            const float bb = bias[n];
#pragma unroll
            for (int i = 0; i < 4; i++) {
#pragma unroll
                for (int g = 0; g < 4; g++) {
                    const int m  = m0 + i * 16 + quad * 4 + g;
                    const int b_ = m >> 10, l = m & 1023;
                    out[(((size_t)(b_ * NHH) + h_) * SS + l) * DD + d_] =
                        f2bu((acc[i][j][g] + bb) * sc);
                }
            }
        }
    }
}

// ---------------------------------------------------------------------------
// Kernel 2: MFMA flash attention, S^T formulation.  R0 VERBATIM (254 us).
//   Ledger (R2-R8): body arithmetic, barrier structure, occupancy pin, LDS
//   footprint, XCD swizzle, and 2-job outer loop ALL regressed.
//   R6: FETCH 71->13.5 MB changed nothing -> not memory-bound.
//   R8: full co-residency (512 blocks = 2/CU exact) left occupancy at 23%
//   -> per-wave latency-bound; 23% is the body's operating point.
//   Do not edit this kernel.
//   S^T = K Q^T  (Q pre-scaled by 1/8)  -> C[r=quad*4+g][l=lq] per 16x16
//   QE = Q E^T, KE' = (K E^T)*0.125 + mask  -> transposed packed LDS stores
//   score = S^T + QE[l][t] + KE'[r][t],  t = l_loc - r_loc + 63
//   softmax over r (per-lane scalar state, cross-quad shuffles)
//   P^T packs straight from C-registers -> wave-local LDS -> B-operand
//   O^T += V^T P^T  (V^T A-frags direct from global)
// grid (16, 16, 4), block 256.  LDS 44,032 B.
// ---------------------------------------------------------------------------
__global__ __launch_bounds__(256)
void attn_mfma(const ushort_t* __restrict__ qb, const ushort_t* __restrict__ kb,
               const ushort_t* __restrict__ vt, const ushort_t* __restrict__ Eb,
               const float* __restrict__ mask, ushort_t* __restrict__ ctx)
{
    const int l0 = blockIdx.x * 64;
    const int h  = blockIdx.y, b = blockIdx.z;
    const int tid  = threadIdx.x;
    const int w    = tid >> 6;
    const int lane = tid & 63;
    const int quad = lane >> 4, lq = lane & 15;

    // LDS: 2*128*68*2 + 64*72*2 = 44,032 B
    __shared__ __align__(16) ushort_t QEsT[128 * 68];   // [t][l]
    __shared__ __align__(16) ushort_t KEsT[128 * 68];   // [t][r]
    __shared__ __align__(16) ushort_t PsT [64 * 72];    // [l][r]

    const ushort_t* qbh = qb + (size_t)(b * NHH + h) * SS * DD;
    const ushort_t* kbh = kb + (size_t)(b * NHH + h) * SS * DD;
    const ushort_t* vth = vt + (size_t)(b * NHH + h) * DD * SS;   // [d][s]

    // Q B-frag (pre-scaled): rows l = l0 + w*16 + lq
    short8 qa0, qa1;
    {
        const ushort_t* p = qbh + (l0 + w * 16 + lq) * DD + quad * 8;
        qa0 = *(const short8*)p;
        qa1 = *(const short8*)(p + 32);
    }
    const int l_loc = w * 16 + lq;

    f32x4 Oacc[4];
#pragma unroll
    for (int dt = 0; dt < 4; dt++) Oacc[dt] = (f32x4){0.f, 0.f, 0.f, 0.f};
    float mrow = -3e38f, lrow = 0.f;

    for (int rt = 0; rt < 16; rt++) {
        const int r0   = rt * 64;
        const int dmin = l0 - r0 + 960;

        // K fragments (rows r0 + ct*16 + lq)
        short8 kf0[4], kf1[4];
#pragma unroll
        for (int ct = 0; ct < 4; ct++) {
            const ushort_t* p = kbh + (r0 + ct * 16 + lq) * DD + quad * 8;
            kf0[ct] = *(const short8*)p;
            kf1[ct] = *(const short8*)(p + 32);
        }
        // mask values for KE fold (rows r = r0 + w*16 + quad*4 + g)
        float mk[4];
#pragma unroll
        for (int g = 0; g < 4; g++) mk[g] = mask[b * SS + r0 + w * 16 + quad * 4 + g];

        __syncthreads();   // prior tile's QEsT/KEsT reads done

        // --- QE / KE' via MFMA, transposed packed stores ---
#pragma unroll
        for (int tt = 0; tt < 8; tt++) {
            const ushort_t* ep = Eb + (size_t)(dmin + tt * 16 + lq) * DD + quad * 8;
            short8 e0 = *(const short8*)ep;
            short8 e1 = *(const short8*)(ep + 32);
            f32x4 qe = (f32x4){0.f, 0.f, 0.f, 0.f};
            f32x4 ke = (f32x4){0.f, 0.f, 0.f, 0.f};
            qe = MFMA_16x16x32(qa0, e0, qe);
            qe = MFMA_16x16x32(qa1, e1, qe);
            ke = MFMA_16x16x32(kf0[w], e0, ke);
            ke = MFMA_16x16x32(kf1[w], e1, ke);
            us4 pq, pk;
#pragma unroll
            for (int g = 0; g < 4; g++) {
                pq[g] = f2bu(qe[g]);                       // already /8 via Q
                pk[g] = f2bu(ke[g] * 0.125f + mk[g]);      // mask folded in
            }
            const int trow = tt * 16 + lq;
            *(us4*)&QEsT[trow * 68 + w * 16 + quad * 4] = pq;
            *(us4*)&KEsT[trow * 68 + w * 16 + quad * 4] = pk;
        }

        // --- S^T = K Q^T for this wave's l-block ---
        f32x4 st[4];
#pragma unroll
        for (int ct = 0; ct < 4; ct++) {
            f32x4 a = (f32x4){0.f, 0.f, 0.f, 0.f};
            a = MFMA_16x16x32(kf0[ct], qa0, a);
            a = MFMA_16x16x32(kf1[ct], qa1, a);
            st[ct] = a;
        }

        __syncthreads();   // QEsT/KEsT visible (KEsT is cross-wave)

        // --- scores + online softmax (per-lane l fixed) ---
        float p[4][4];
        float tmax = -3e38f;
#pragma unroll
        for (int ct = 0; ct < 4; ct++) {
#pragma unroll
            for (int g = 0; g < 4; g++) {
                const int r_loc = ct * 16 + quad * 4 + g;
                const int t = l_loc - r_loc + 63;      // [0,126]
                float s = st[ct][g] + bu2f(QEsT[t * 68 + l_loc])
                                    + bu2f(KEsT[t * 68 + r_loc]);
                p[ct][g] = s;
                tmax = fmaxf(tmax, s);
            }
        }
        tmax = fmaxf(tmax, __shfl_xor(tmax, 16));
        tmax = fmaxf(tmax, __shfl_xor(tmax, 32));
        const float mnew  = fmaxf(mrow, tmax);
        const float alpha = __expf(mrow - mnew);
        mrow = mnew;
        float psum = 0.f;
#pragma unroll
        for (int ct = 0; ct < 4; ct++)
#pragma unroll
            for (int g = 0; g < 4; g++) {
                const float e = __expf(p[ct][g] - mrow);
                p[ct][g] = e;
                psum += e;
            }
        psum += __shfl_xor(psum, 16);
        psum += __shfl_xor(psum, 32);
        lrow = lrow * alpha + psum;
#pragma unroll
        for (int dt = 0; dt < 4; dt++)
#pragma unroll
            for (int g = 0; g < 4; g++) Oacc[dt][g] *= alpha;

        // --- P^T -> LDS (wave-local rows, packed) ---
#pragma unroll
        for (int ct = 0; ct < 4; ct++) {
            us4 pp;
#pragma unroll
            for (int g = 0; g < 4; g++) pp[g] = f2bu(p[ct][g]);
            *(us4*)&PsT[l_loc * 72 + ct * 16 + quad * 4] = pp;
        }

        // --- O^T += V^T P^T (no barrier: PsT rows are wave-local) ---
#pragma unroll
        for (int c = 0; c < 2; c++) {
            short8 pb = *(const short8*)&PsT[l_loc * 72 + c * 32 + quad * 8];
#pragma unroll
            for (int dt = 0; dt < 4; dt++) {
                const ushort_t* vp = vth + (size_t)(dt * 16 + lq) * SS
                                         + r0 + c * 32 + quad * 8;
                short8 va = *(const short8*)vp;
                Oacc[dt] = MFMA_16x16x32(va, pb, Oacc[dt]);
            }
        }
    }

    // --- epilogue: ctx[b, l, h*64 + d] bf16, packed us4 over d ---
    const float invl = 1.0f / lrow;
    ushort_t* cbase = ctx + (size_t)(b * SS + l0 + w * 16 + lq) * HH + h * DD;
#pragma unroll
    for (int dt = 0; dt < 4; dt++) {
        us4 po;
#pragma unroll
        for (int g = 0; g < 4; g++) po[g] = f2bu(Oacc[dt][g] * invl);
        *(us4*)(cbase + dt * 16 + quad * 4) = po;
    }
}

// ---------------------------------------------------------------------------
// Kernel 3: output projection, MFMA.  y = ctx @ Wo^T + bo + x  (fp32 out).
//   R10: tile 128x128 -> 128x64 (grid (16,32) = 512 blocks = 2 blocks/CU):
//   at (8,32) = 1 block/CU the 2-barrier staging structure has no co-resident
//   independent block to hide the per-K-step stage drain (m114 overlap model).
//   Staging pattern and epilogue indexing otherwise unchanged (both verified).
// grid (16, 32), block 256 (4 waves, 2x2 of 64x32).  LDS 12 KB.
// ---------------------------------------------------------------------------
__global__ __launch_bounds__(256)
void out_proj(const ushort_t* __restrict__ ctx, const ushort_t* __restrict__ Wob,
              const float* __restrict__ bo, const float* __restrict__ x,
              float* __restrict__ y)
{
    const int tid = threadIdx.x, w = tid >> 6, lane = tid & 63;
    const int quad = lane >> 4, lq = lane & 15;
    const int wm = w >> 1, wn = w & 1;
    const int bm = blockIdx.y * 128;
    const int bn = blockIdx.x * 64;
    const int m0 = bm + wm * 64;
    const int n0 = bn + wn * 32;

    __shared__ __align__(16) ushort_t As[128 * 32];   // A rows bm..bm+127
    __shared__ __align__(16) ushort_t Bs[ 64 * 32];   // Wo rows bn..bn+63

    f32x4 acc[4][2];
#pragma unroll
    for (int i = 0; i < 4; i++)
#pragma unroll
        for (int j = 0; j < 2; j++) acc[i][j] = (f32x4){0.f, 0.f, 0.f, 0.f};

    // Staging: A = 8 chunks (wave w does c=w, w+4); B = 4 chunks (wave w does c=w).
    const int lrow = lane >> 2;
    const int lcol = (lane & 3) * 8;
    const ushort_t* aS0 = ctx + (size_t)(bm + w * 16 + lrow) * 1024 + lcol;
    const ushort_t* aS1 = aS0 + 64 * 1024;
    const ushort_t* bS0 = Wob + (size_t)(bn + w * 16 + lrow) * 1024 + lcol;
    ushort_t* const aD0 = As + w * 512;
    ushort_t* const aD1 = As + (w + 4) * 512;
    ushort_t* const bD0 = Bs + w * 512;

    for (int k0 = 0; k0 < 1024; k0 += 32) {
        __syncthreads();
        stage16(aS0 + k0, aD0);
        stage16(aS1 + k0, aD1);
        stage16(bS0 + k0, bD0);
        __syncthreads();

        short8 af[4], bf[2];
#pragma unroll
        for (int i = 0; i < 4; i++)
            af[i] = *(const short8*)&As[(wm * 64 + i * 16 + lq) * 32 + quad * 8];
#pragma unroll
        for (int j = 0; j < 2; j++)
            bf[j] = *(const short8*)&Bs[(wn * 32 + j * 16 + lq) * 32 + quad * 8];
#pragma unroll
        for (int i = 0; i < 4; i++)
#pragma unroll
            for (int j = 0; j < 2; j++)
                acc[i][j] = MFMA_16x16x32(af[i], bf[j], acc[i][j]);
    }

#pragma unroll
    for (int j = 0; j < 2; j++) {
        const int n = n0 + j * 16 + lq;
        const float bb = bo[n];
#pragma unroll
        for (int i = 0; i < 4; i++) {
#pragma unroll
            for (int g = 0; g < 4; g++) {
                const int m = m0 + i * 16 + quad * 4 + g;
                y[(size_t)m * 1024 + n] = acc[i][j][g] + bb + x[(size_t)m * 1024 + n];
            }
        }
    }
}

// ---------------------------------------------------------------------------
// Kernel 4: LayerNorm per row (float4), fp32 out.  grid 4096, block 256.
// ---------------------------------------------------------------------------
__global__ void layernorm(const float* __restrict__ y, const float* __restrict__ g,
                          const float* __restrict__ beta, float* __restrict__ out)
{
    const int row = blockIdx.x;
    const int tid = threadIdx.x;

    __shared__ float red[256];
    __shared__ float red2[256];

    const float4 t4 = *(const float4*)(y + (size_t)row * 1024 + tid * 4);
    float s  = t4.x + t4.y + t4.z + t4.w;
    float s2 = t4.x * t4.x + t4.y * t4.y + t4.z * t4.z + t4.w * t4.w;
    red[tid] = s;
    red2[tid] = s2;
    __syncthreads();
    for (int st = 128; st > 0; st >>= 1) {
        if (tid < st) { red[tid] += red[tid + st]; red2[tid] += red2[tid + st]; }
        __syncthreads();
    }
    const float mu  = red[0] * (1.0f / 1024.0f);
    const float var = red2[0] * (1.0f / 1024.0f) - mu * mu;
    const float rs  = rsqrtf(var + 1e-12f);

    const float4 g4 = *(const float4*)(g + tid * 4);
    const float4 b4 = *(const float4*)(beta + tid * 4);
    float4 o;
    o.x = (t4.x - mu) * rs * g4.x + b4.x;
    o.y = (t4.y - mu) * rs * g4.y + b4.y;
    o.z = (t4.z - mu) * rs * g4.z + b4.z;
    o.w = (t4.w - mu) * rs * g4.w + b4.w;
    *(float4*)(out + (size_t)row * 1024 + tid * 4) = o;
}

// ---------------------------------------------------------------------------
extern "C" void kernel_launch(void* const* d_in, const int* in_sizes, int n_in,
                              void* d_out, int out_size, void* d_ws, size_t ws_size,
                              hipStream_t stream)
{
    const float* x    = (const float*)d_in[0];
    const float* mask = (const float*)d_in[1];
    const float* Wq   = (const float*)d_in[2];
    const float* bq   = (const float*)d_in[3];
    const float* Wk   = (const float*)d_in[4];
    const float* bk   = (const float*)d_in[5];
    const float* Wv   = (const float*)d_in[6];
    const float* bv   = (const float*)d_in[7];
    const float* dist = (const float*)d_in[8];
    const float* Wo   = (const float*)d_in[9];
    const float* bo   = (const float*)d_in[10];
    const float* g    = (const float*)d_in[11];
    const float* be   = (const float*)d_in[12];

    // ws bytes (40.25 MB, <= 44 MB proven-safe):
    //  xb [0,8M) | Wqb [8,10M) Wkb [10,12M) Wvb [12,14M) Wob [14,16M)
    //  qb [16,24M) kb [24,32M) vt [32,40M) (V^T [B,NH,D,S]) | Eb [40,40.25M)
    //  y fp32 overlays [16,32M) (qb/kb dead after attn)
    // d_out scratch: ctx bf16 until layernorm overwrites fp32.
    char* wsb = (char*)d_ws;
    ushort_t* xb  = (ushort_t*)(wsb);
    ushort_t* Wqb = (ushort_t*)(wsb + ( 8u << 20));
    ushort_t* Wkb = (ushort_t*)(wsb + (10u << 20));
    ushort_t* Wvb = (ushort_t*)(wsb + (12u << 20));
    ushort_t* Wob = (ushort_t*)(wsb + (14u << 20));
    ushort_t* qbu = (ushort_t*)(wsb + (16u << 20));
    ushort_t* kbu = (ushort_t*)(wsb + (24u << 20));
    ushort_t* vtb = (ushort_t*)(wsb + (32u << 20));
    ushort_t* Eb  = (ushort_t*)(wsb + (40u << 20));
    float*    y   = (float*)(wsb + (16u << 20));
    ushort_t* ctxb = (ushort_t*)d_out;

    conv_all<<<8320, 256, 0, stream>>>(x, Wq, Wk, Wv, Wo, dist,
                                       xb, Wqb, Wkb, Wvb, Wob, Eb);
    qkv_mfma<<<dim3(8, 32, 3), 256, 0, stream>>>(xb, Wqb, bq, Wkb, bk, Wvb, bv,
                                                 qbu, kbu, vtb);
    attn_mfma<<<dim3(16, 16, 4), 256, 0, stream>>>(qbu, kbu, vtb, Eb, mask, ctxb);
    out_proj<<<dim3(16, 32), 256, 0, stream>>>(ctxb, Wob, bo, x, y);
    layernorm<<<4096, 256, 0, stream>>>(y, g, be, (float*)d_out);
}

// Round 11
// 405.784 us; speedup vs baseline: 1.4521x; 1.0018x over previous
//
#include <hip/hip_runtime.h>
#include <hip/hip_bf16.h>

#define BB 4
#define SS 1024
#define HH 1024
#define NHH 16
#define DD 64
#define MAXPOS 1024

typedef __hip_bfloat16 bf16;
typedef unsigned short ushort_t;
typedef __attribute__((ext_vector_type(8))) short short8;
typedef __attribute__((ext_vector_type(4))) float f32x4;
typedef __attribute__((ext_vector_type(4))) unsigned short us4;

#define MFMA_16x16x32(a, b, c) __builtin_amdgcn_mfma_f32_16x16x32_bf16((a), (b), (c), 0, 0, 0)

__device__ __forceinline__ float bu2f(ushort_t u) {
    union { unsigned int i; float f; } c; c.i = ((unsigned int)u) << 16; return c.f;
}
__device__ __forceinline__ ushort_t f2bu(float f) {
    __hip_bfloat16 h = __float2bfloat16(f);
    return *reinterpret_cast<ushort_t*>(&h);
}
// async global->LDS, 16B per lane.  LDS dest must be WAVE-UNIFORM base
// (HW adds lane*16); global src is per-lane.  [m97/m104]
__device__ __forceinline__ void stage16(const ushort_t* g, ushort_t* l) {
    __builtin_amdgcn_global_load_lds(
        (const __attribute__((address_space(1))) void*)g,
        (__attribute__((address_space(3))) void*)l,
        16, 0, 0);
}

// ---------------------------------------------------------------------------
// Kernel 0: all fp32->bf16 conversions in one launch (x, 4 weights, E).
// Segments in units of float4/us4 groups:
//   x [0, 1048576) | Wq +262144 | Wk | Wv | Wo -> 2097152 | E [.., 2129920)
// E: 2047*64 = 131008 valid floats = 32752 groups; rest zero (row 2047).
// ---------------------------------------------------------------------------
__global__ void conv_all(const float* __restrict__ x,  const float* __restrict__ Wq,
                         const float* __restrict__ Wk, const float* __restrict__ Wv,
                         const float* __restrict__ Wo, const float* __restrict__ dist,
                         ushort_t* __restrict__ xb,  ushort_t* __restrict__ Wqb,
                         ushort_t* __restrict__ Wkb, ushort_t* __restrict__ Wvb,
                         ushort_t* __restrict__ Wob, ushort_t* __restrict__ Eb)
{
    const int i = blockIdx.x * 256 + threadIdx.x;
    const float* src; ushort_t* dst; int off;
    if (i < 1048576)      { src = x;  dst = xb;  off = i; }
    else if (i < 1310720) { src = Wq; dst = Wqb; off = i - 1048576; }
    else if (i < 1572864) { src = Wk; dst = Wkb; off = i - 1310720; }
    else if (i < 1835008) { src = Wv; dst = Wvb; off = i - 1572864; }
    else if (i < 2097152) { src = Wo; dst = Wob; off = i - 1835008; }
    else if (i < 2129920) {
        const int j = i - 2097152;
        float4 f = (j < 32752) ? ((const float4*)dist)[j] : make_float4(0.f, 0.f, 0.f, 0.f);
        us4 u;
        u[0] = f2bu(f.x); u[1] = f2bu(f.y); u[2] = f2bu(f.z); u[3] = f2bu(f.w);
        ((us4*)Eb)[j] = u;
        return;
    } else return;
    float4 f = ((const float4*)src)[off];
    us4 u;
    u[0] = f2bu(f.x); u[1] = f2bu(f.y); u[2] = f2bu(f.z); u[3] = f2bu(f.w);
    ((us4*)dst)[off] = u;
}

// ---------------------------------------------------------------------------
// Kernel 1: QKV projection, MFMA.  C = xb @ W^T (+bias).
//   R11: tile 128x128 -> 128x64 (grid (16,32,3) = 1536 blocks), mirroring
//   R10's verified out_proj change: residency 3 -> ~4 blocks/CU so the
//   per-K-step stage drain is hidden by more co-resident independent blocks
//   (m114 overlap model; R10 confirmed on out_proj 1->2).
//   m97-structure staging: A [128][32] (8 chunks), B [64][32] (4 chunks)
//   via global_load_lds width 16, 2 barriers/K-step.
//   Q -> [B,NH,S,D], PRE-SCALED by 0.125 (exact in bf16)
//   K -> [B,NH,S,D]
//   V -> [B,NH,D,S]  (transposed: PV A-operand reads rows of V^T directly)
// grid (16, 32, 3), block 256 (4 waves, 2x2 of 64x32).  LDS 12 KB.
// ---------------------------------------------------------------------------
__global__ __launch_bounds__(256)
void qkv_mfma(const ushort_t* __restrict__ xb,
              const ushort_t* __restrict__ Wqb, const float* __restrict__ bq,
              const ushort_t* __restrict__ Wkb, const float* __restrict__ bk,
              const ushort_t* __restrict__ Wvb, const float* __restrict__ bv,
              ushort_t* __restrict__ q, ushort_t* __restrict__ k,
              ushort_t* __restrict__ vt)
{
    const int which = blockIdx.z;
    const ushort_t* __restrict__ W    = (which == 0) ? Wqb : (which == 1) ? Wkb : Wvb;
    const float*    __restrict__ bias = (which == 0) ? bq  : (which == 1) ? bk  : bv;

    const int tid = threadIdx.x, w = tid >> 6, lane = tid & 63;
    const int quad = lane >> 4, lq = lane & 15;
    const int wm = w >> 1, wn = w & 1;
    const int bm = blockIdx.y * 128;          // block row base
    const int bn = blockIdx.x * 64;           // block col base
    const int m0 = bm + wm * 64;
    const int n0 = bn + wn * 32;

    __shared__ __align__(16) ushort_t As[128 * 32];   // rows bm..bm+127
    __shared__ __align__(16) ushort_t Bs[ 64 * 32];   // rows bn..bn+63

    f32x4 acc[4][2];
#pragma unroll
    for (int i = 0; i < 4; i++)
#pragma unroll
        for (int j = 0; j < 2; j++) acc[i][j] = (f32x4){0.f, 0.f, 0.f, 0.f};

    // Staging map: chunk c (1024 B = 16 rows) at LDS byte c*1024 + lane*16.
    // lane L -> row c*16 + L/4, col (L&3)*8 (bf16).
    // A: wave w covers chunks {w, w+4}; B: wave w covers chunk w.
    const int lrow = lane >> 2;
    const int lcol = (lane & 3) * 8;
    const ushort_t* aS0 = xb + (size_t)(bm + w * 16 + lrow) * 1024 + lcol;
    const ushort_t* aS1 = aS0 + 64 * 1024;     // chunk w+4 = +64 rows
    const ushort_t* bS0 = W  + (size_t)(bn + w * 16 + lrow) * 1024 + lcol;
    ushort_t* const aD0 = As + w * 512;        // wave-uniform LDS bases
    ushort_t* const aD1 = As + (w + 4) * 512;
    ushort_t* const bD0 = Bs + w * 512;

    for (int k0 = 0; k0 < 1024; k0 += 32) {
        __syncthreads();                       // prior iter's ds_reads done
        stage16(aS0 + k0, aD0);
        stage16(aS1 + k0, aD1);
        stage16(bS0 + k0, bD0);
        __syncthreads();                       // vmcnt(0) drained by barrier

        short8 af[4], bf[2];
#pragma unroll
        for (int i = 0; i < 4; i++)
            af[i] = *(const short8*)&As[(wm * 64 + i * 16 + lq) * 32 + quad * 8];
#pragma unroll
        for (int j = 0; j < 2; j++)
            bf[j] = *(const short8*)&Bs[(wn * 32 + j * 16 + lq) * 32 + quad * 8];
#pragma unroll
        for (int i = 0; i < 4; i++)
#pragma unroll
            for (int j = 0; j < 2; j++)
                acc[i][j] = MFMA_16x16x32(af[i], bf[j], acc[i][j]);
    }

    if (which == 2) {
        // V^T: out[((b*NH+h)*D + d)*S + l], l = m-index (contiguous in g)
#pragma unroll
        for (int j = 0; j < 2; j++) {
            const int n  = n0 + j * 16 + lq;
            const int h_ = n >> 6, d_ = n & 63;
            const float bb = bias[n];
#pragma unroll
            for (int i = 0; i < 4; i++) {
                const int m  = m0 + i * 16 + quad * 4;   // g=0 row
                const int b_ = m >> 10, l = m & 1023;
                us4 pv;
#pragma unroll
                for (int g = 0; g < 4; g++) pv[g] = f2bu(acc[i][j][g] + bb);
                *(us4*)(vt + (((size_t)(b_ * NHH) + h_) * DD + d_) * SS + l) = pv;
            }
        }
    } else {
        ushort_t* __restrict__ out = (which == 0) ? q : k;
        const float sc = (which == 0) ? 0.125f : 1.0f;
#pragma unroll
        for (int j = 0; j < 2; j++) {
            const int n  = n0 + j * 16 + lq;
            const int h_ = n >> 6, d_ = n & 63;
            const float bb = bias[n];
#pragma unroll
            for (int i = 0; i < 4; i++) {
#pragma unroll
                for (int g = 0; g < 4; g++) {
                    const int m  = m0 + i * 16 + quad * 4 + g;
                    const int b_ = m >> 10, l = m & 1023;
                    out[(((size_t)(b_ * NHH) + h_) * SS + l) * DD + d_] =
                        f2bu((acc[i][j][g] + bb) * sc);
                }
            }
        }
    }
}

// ---------------------------------------------------------------------------
// Kernel 2: MFMA flash attention, S^T formulation.  R0 VERBATIM (254 us).
//   Ledger (R2-R8): body arithmetic, barrier structure, occupancy pin, LDS
//   footprint, XCD swizzle, and 2-job outer loop ALL regressed.
//   R6: FETCH 71->13.5 MB changed nothing -> not memory-bound.
//   R8: full co-residency (512 blocks = 2/CU exact) left occupancy at 23%
//   -> per-wave latency-bound; 23% is the body's operating point.
//   Do not edit this kernel.
//   S^T = K Q^T  (Q pre-scaled by 1/8)  -> C[r=quad*4+g][l=lq] per 16x16
//   QE = Q E^T, KE' = (K E^T)*0.125 + mask  -> transposed packed LDS stores
//   score = S^T + QE[l][t] + KE'[r][t],  t = l_loc - r_loc + 63
//   softmax over r (per-lane scalar state, cross-quad shuffles)
//   P^T packs straight from C-registers -> wave-local LDS -> B-operand
//   O^T += V^T P^T  (V^T A-frags direct from global)
// grid (16, 16, 4), block 256.  LDS 44,032 B.
// ---------------------------------------------------------------------------
__global__ __launch_bounds__(256)
void attn_mfma(const ushort_t* __restrict__ qb, const ushort_t* __restrict__ kb,
               const ushort_t* __restrict__ vt, const ushort_t* __restrict__ Eb,
               const float* __restrict__ mask, ushort_t* __restrict__ ctx)
{
    const int l0 = blockIdx.x * 64;
    const int h  = blockIdx.y, b = blockIdx.z;
    const int tid  = threadIdx.x;
    const int w    = tid >> 6;
    const int lane = tid & 63;
    const int quad = lane >> 4, lq = lane & 15;

    // LDS: 2*128*68*2 + 64*72*2 = 44,032 B
    __shared__ __align__(16) ushort_t QEsT[128 * 68];   // [t][l]
    __shared__ __align__(16) ushort_t KEsT[128 * 68];   // [t][r]
    __shared__ __align__(16) ushort_t PsT [64 * 72];    // [l][r]

    const ushort_t* qbh = qb + (size_t)(b * NHH + h) * SS * DD;
    const ushort_t* kbh = kb + (size_t)(b * NHH + h) * SS * DD;
    const ushort_t* vth = vt + (size_t)(b * NHH + h) * DD * SS;   // [d][s]

    // Q B-frag (pre-scaled): rows l = l0 + w*16 + lq
    short8 qa0, qa1;
    {
        const ushort_t* p = qbh + (l0 + w * 16 + lq) * DD + quad * 8;
        qa0 = *(const short8*)p;
        qa1 = *(const short8*)(p + 32);
    }
    const int l_loc = w * 16 + lq;

    f32x4 Oacc[4];
#pragma unroll
    for (int dt = 0; dt < 4; dt++) Oacc[dt] = (f32x4){0.f, 0.f, 0.f, 0.f};
    float mrow = -3e38f, lrow = 0.f;

    for (int rt = 0; rt < 16; rt++) {
        const int r0   = rt * 64;
        const int dmin = l0 - r0 + 960;

        // K fragments (rows r0 + ct*16 + lq)
        short8 kf0[4], kf1[4];
#pragma unroll
        for (int ct = 0; ct < 4; ct++) {
            const ushort_t* p = kbh + (r0 + ct * 16 + lq) * DD + quad * 8;
            kf0[ct] = *(const short8*)p;
            kf1[ct] = *(const short8*)(p + 32);
        }
        // mask values for KE fold (rows r = r0 + w*16 + quad*4 + g)
        float mk[4];
#pragma unroll
        for (int g = 0; g < 4; g++) mk[g] = mask[b * SS + r0 + w * 16 + quad * 4 + g];

        __syncthreads();   // prior tile's QEsT/KEsT reads done

        // --- QE / KE' via MFMA, transposed packed stores ---
#pragma unroll
        for (int tt = 0; tt < 8; tt++) {
            const ushort_t* ep = Eb + (size_t)(dmin + tt * 16 + lq) * DD + quad * 8;
            short8 e0 = *(const short8*)ep;
            short8 e1 = *(const short8*)(ep + 32);
            f32x4 qe = (f32x4){0.f, 0.f, 0.f, 0.f};
            f32x4 ke = (f32x4){0.f, 0.f, 0.f, 0.f};
            qe = MFMA_16x16x32(qa0, e0, qe);
            qe = MFMA_16x16x32(qa1, e1, qe);
            ke = MFMA_16x16x32(kf0[w], e0, ke);
            ke = MFMA_16x16x32(kf1[w], e1, ke);
            us4 pq, pk;
#pragma unroll
            for (int g = 0; g < 4; g++) {
                pq[g] = f2bu(qe[g]);                       // already /8 via Q
                pk[g] = f2bu(ke[g] * 0.125f + mk[g]);      // mask folded in
            }
            const int trow = tt * 16 + lq;
            *(us4*)&QEsT[trow * 68 + w * 16 + quad * 4] = pq;
            *(us4*)&KEsT[trow * 68 + w * 16 + quad * 4] = pk;
        }

        // --- S^T = K Q^T for this wave's l-block ---
        f32x4 st[4];
#pragma unroll
        for (int ct = 0; ct < 4; ct++) {
            f32x4 a = (f32x4){0.f, 0.f, 0.f, 0.f};
            a = MFMA_16x16x32(kf0[ct], qa0, a);
            a = MFMA_16x16x32(kf1[ct], qa1, a);
            st[ct] = a;
        }

        __syncthreads();   // QEsT/KEsT visible (KEsT is cross-wave)

        // --- scores + online softmax (per-lane l fixed) ---
        float p[4][4];
        float tmax = -3e38f;
#pragma unroll
        for (int ct = 0; ct < 4; ct++) {
#pragma unroll
            for (int g = 0; g < 4; g++) {
                const int r_loc = ct * 16 + quad * 4 + g;
                const int t = l_loc - r_loc + 63;      // [0,126]
                float s = st[ct][g] + bu2f(QEsT[t * 68 + l_loc])
                                    + bu2f(KEsT[t * 68 + r_loc]);
                p[ct][g] = s;
                tmax = fmaxf(tmax, s);
            }
        }
        tmax = fmaxf(tmax, __shfl_xor(tmax, 16));
        tmax = fmaxf(tmax, __shfl_xor(tmax, 32));
        const float mnew  = fmaxf(mrow, tmax);
        const float alpha = __expf(mrow - mnew);
        mrow = mnew;
        float psum = 0.f;
#pragma unroll
        for (int ct = 0; ct < 4; ct++)
#pragma unroll
            for (int g = 0; g < 4; g++) {
                const float e = __expf(p[ct][g] - mrow);
                p[ct][g] = e;
                psum += e;
            }
        psum += __shfl_xor(psum, 16);
        psum += __shfl_xor(psum, 32);
        lrow = lrow * alpha + psum;
#pragma unroll
        for (int dt = 0; dt < 4; dt++)
#pragma unroll
            for (int g = 0; g < 4; g++) Oacc[dt][g] *= alpha;

        // --- P^T -> LDS (wave-local rows, packed) ---
#pragma unroll
        for (int ct = 0; ct < 4; ct++) {
            us4 pp;
#pragma unroll
            for (int g = 0; g < 4; g++) pp[g] = f2bu(p[ct][g]);
            *(us4*)&PsT[l_loc * 72 + ct * 16 + quad * 4] = pp;
        }

        // --- O^T += V^T P^T (no barrier: PsT rows are wave-local) ---
#pragma unroll
        for (int c = 0; c < 2; c++) {
            short8 pb = *(const short8*)&PsT[l_loc * 72 + c * 32 + quad * 8];
#pragma unroll
            for (int dt = 0; dt < 4; dt++) {
                const ushort_t* vp = vth + (size_t)(dt * 16 + lq) * SS
                                         + r0 + c * 32 + quad * 8;
                short8 va = *(const short8*)vp;
                Oacc[dt] = MFMA_16x16x32(va, pb, Oacc[dt]);
            }
        }
    }

    // --- epilogue: ctx[b, l, h*64 + d] bf16, packed us4 over d ---
    const float invl = 1.0f / lrow;
    ushort_t* cbase = ctx + (size_t)(b * SS + l0 + w * 16 + lq) * HH + h * DD;
#pragma unroll
    for (int dt = 0; dt < 4; dt++) {
        us4 po;
#pragma unroll
        for (int g = 0; g < 4; g++) po[g] = f2bu(Oacc[dt][g] * invl);
        *(us4*)(cbase + dt * 16 + quad * 4) = po;
    }
}

// ---------------------------------------------------------------------------
// Kernel 3: output projection, MFMA.  y = ctx @ Wo^T + bo + x  (fp32 out).
//   R10-verified: tile 128x64, grid (16,32) = 512 blocks = 2 blocks/CU
//   (at 1 block/CU the stage drain was exposed; R10 measured the win).
// grid (16, 32), block 256 (4 waves, 2x2 of 64x32).  LDS 12 KB.
// ---------------------------------------------------------------------------
__global__ __launch_bounds__(256)
void out_proj(const ushort_t* __restrict__ ctx, const ushort_t* __restrict__ Wob,
              const float* __restrict__ bo, const float* __restrict__ x,
              float* __restrict__ y)
{
    const int tid = threadIdx.x, w = tid >> 6, lane = tid & 63;
    const int quad = lane >> 4, lq = lane & 15;
    const int wm = w >> 1, wn = w & 1;
    const int bm = blockIdx.y * 128;
    const int bn = blockIdx.x * 64;
    const int m0 = bm + wm * 64;
    const int n0 = bn + wn * 32;

    __shared__ __align__(16) ushort_t As[128 * 32];   // A rows bm..bm+127
    __shared__ __align__(16) ushort_t Bs[ 64 * 32];   // Wo rows bn..bn+63

    f32x4 acc[4][2];
#pragma unroll
    for (int i = 0; i < 4; i++)
#pragma unroll
        for (int j = 0; j < 2; j++) acc[i][j] = (f32x4){0.f, 0.f, 0.f, 0.f};

    // Staging: A = 8 chunks (wave w does c=w, w+4); B = 4 chunks (wave w does c=w).
    const int lrow = lane >> 2;
    const int lcol = (lane & 3) * 8;
    const ushort_t* aS0 = ctx + (size_t)(bm + w * 16 + lrow) * 1024 + lcol;
    const ushort_t* aS1 = aS0 + 64 * 1024;
    const ushort_t* bS0 = Wob + (size_t)(bn + w * 16 + lrow) * 1024 + lcol;
    ushort_t* const aD0 = As + w * 512;
    ushort_t* const aD1 = As + (w + 4) * 512;
    ushort_t* const bD0 = Bs + w * 512;

    for (int k0 = 0; k0 < 1024; k0 += 32) {
        __syncthreads();
        stage16(aS0 + k0, aD0);
        stage16(aS1 + k0, aD1);
        stage16(bS0 + k0, bD0);
        __syncthreads();

        short8 af[4], bf[2];
#pragma unroll
        for (int i = 0; i < 4; i++)
            af[i] = *(const short8*)&As[(wm * 64 + i * 16 + lq) * 32 + quad * 8];
#pragma unroll
        for (int j = 0; j < 2; j++)
            bf[j] = *(const short8*)&Bs[(wn * 32 + j * 16 + lq) * 32 + quad * 8];
#pragma unroll
        for (int i = 0; i < 4; i++)
#pragma unroll
            for (int j = 0; j < 2; j++)
                acc[i][j] = MFMA_16x16x32(af[i], bf[j], acc[i][j]);
    }

#pragma unroll
    for (int j = 0; j < 2; j++) {
        const int n = n0 + j * 16 + lq;
        const float bb = bo[n];
#pragma unroll
        for (int i = 0; i < 4; i++) {
#pragma unroll
            for (int g = 0; g < 4; g++) {
                const int m = m0 + i * 16 + quad * 4 + g;
                y[(size_t)m * 1024 + n] = acc[i][j][g] + bb + x[(size_t)m * 1024 + n];
            }
        }
    }
}

// ---------------------------------------------------------------------------
// Kernel 4: LayerNorm per row (float4), fp32 out.  grid 4096, block 256.
// ---------------------------------------------------------------------------
__global__ void layernorm(const float* __restrict__ y, const float* __restrict__ g,
                          const float* __restrict__ beta, float* __restrict__ out)
{
    const int row = blockIdx.x;
    const int tid = threadIdx.x;

    __shared__ float red[256];
    __shared__ float red2[256];

    const float4 t4 = *(const float4*)(y + (size_t)row * 1024 + tid * 4);
    float s  = t4.x + t4.y + t4.z + t4.w;
    float s2 = t4.x * t4.x + t4.y * t4.y + t4.z * t4.z + t4.w * t4.w;
    red[tid] = s;
    red2[tid] = s2;
    __syncthreads();
    for (int st = 128; st > 0; st >>= 1) {
        if (tid < st) { red[tid] += red[tid + st]; red2[tid] += red2[tid + st]; }
        __syncthreads();
    }
    const float mu  = red[0] * (1.0f / 1024.0f);
    const float var = red2[0] * (1.0f / 1024.0f) - mu * mu;
    const float rs  = rsqrtf(var + 1e-12f);

    const float4 g4 = *(const float4*)(g + tid * 4);
    const float4 b4 = *(const float4*)(beta + tid * 4);
    float4 o;
    o.x = (t4.x - mu) * rs * g4.x + b4.x;
    o.y = (t4.y - mu) * rs * g4.y + b4.y;
    o.z = (t4.z - mu) * rs * g4.z + b4.z;
    o.w = (t4.w - mu) * rs * g4.w + b4.w;
    *(float4*)(out + (size_t)row * 1024 + tid * 4) = o;
}

// ---------------------------------------------------------------------------
extern "C" void kernel_launch(void* const* d_in, const int* in_sizes, int n_in,
                              void* d_out, int out_size, void* d_ws, size_t ws_size,
                              hipStream_t stream)
{
    const float* x    = (const float*)d_in[0];
    const float* mask = (const float*)d_in[1];
    const float* Wq   = (const float*)d_in[2];
    const float* bq   = (const float*)d_in[3];
    const float* Wk   = (const float*)d_in[4];
    const float* bk   = (const float*)d_in[5];
    const float* Wv   = (const float*)d_in[6];
    const float* bv   = (const float*)d_in[7];
    const float* dist = (const float*)d_in[8];
    const float* Wo   = (const float*)d_in[9];
    const float* bo   = (const float*)d_in[10];
    const float* g    = (const float*)d_in[11];
    const float* be   = (const float*)d_in[12];

    // ws bytes (40.25 MB, <= 44 MB proven-safe):
    //  xb [0,8M) | Wqb [8,10M) Wkb [10,12M) Wvb [12,14M) Wob [14,16M)
    //  qb [16,24M) kb [24,32M) vt [32,40M) (V^T [B,NH,D,S]) | Eb [40,40.25M)
    //  y fp32 overlays [16,32M) (qb/kb dead after attn)
    // d_out scratch: ctx bf16 until layernorm overwrites fp32.
    char* wsb = (char*)d_ws;
    ushort_t* xb  = (ushort_t*)(wsb);
    ushort_t* Wqb = (ushort_t*)(wsb + ( 8u << 20));
    ushort_t* Wkb = (ushort_t*)(wsb + (10u << 20));
    ushort_t* Wvb = (ushort_t*)(wsb + (12u << 20));
    ushort_t* Wob = (ushort_t*)(wsb + (14u << 20));
    ushort_t* qbu = (ushort_t*)(wsb + (16u << 20));
    ushort_t* kbu = (ushort_t*)(wsb + (24u << 20));
    ushort_t* vtb = (ushort_t*)(wsb + (32u << 20));
    ushort_t* Eb  = (ushort_t*)(wsb + (40u << 20));
    float*    y   = (float*)(wsb + (16u << 20));
    ushort_t* ctxb = (ushort_t*)d_out;

    conv_all<<<8320, 256, 0, stream>>>(x, Wq, Wk, Wv, Wo, dist,
                                       xb, Wqb, Wkb, Wvb, Wob, Eb);
    qkv_mfma<<<dim3(16, 32, 3), 256, 0, stream>>>(xb, Wqb, bq, Wkb, bk, Wvb, bv,
                                                  qbu, kbu, vtb);
    attn_mfma<<<dim3(16, 16, 4), 256, 0, stream>>>(qbu, kbu, vtb, Eb, mask, ctxb);
    out_proj<<<dim3(16, 32), 256, 0, stream>>>(ctxb, Wob, bo, x, y);
    layernorm<<<4096, 256, 0, stream>>>(y, g, be, (float*)d_out);
}